// Round 3
// baseline (14254.619 us; speedup 1.0000x reference)
//
#include <hip/hip_runtime.h>
#include <hip/hip_bf16.h>
#include <math.h>

// Problem dims (fixed by reference)
#define BB 4
#define SS 2048
#define EE 256
#define HH 8
#define DD 32
#define LL 2
#define NI 1024
#define NROWS (BB*SS)   // 8192

// ---------------------------------------------------------------------------
// Embedding: h[row,:] = wte[ids[row],:] + wpe[row % S,:]
__global__ __launch_bounds__(64) void embed_kernel(
    const int* __restrict__ ids, const float* __restrict__ wte,
    const float* __restrict__ wpe, float* __restrict__ h)
{
    int row  = blockIdx.x;            // b*S + s
    int s    = row & (SS - 1);
    int lane = threadIdx.x;
    int id   = ids[row];
    float4 a = *(const float4*)(wte + (size_t)id * EE + lane * 4);
    float4 p = *(const float4*)(wpe + (size_t)s  * EE + lane * 4);
    float4 o = { a.x + p.x, a.y + p.y, a.z + p.z, a.w + p.w };
    *(float4*)(h + (size_t)row * EE + lane * 4) = o;
}

// ---------------------------------------------------------------------------
// LayerNorm over E=256: one wave (64 lanes) per row, 4 floats/lane.
__global__ __launch_bounds__(64) void ln_kernel(
    const float* __restrict__ in, const float* __restrict__ g,
    const float* __restrict__ b, float* __restrict__ out)
{
    int row  = blockIdx.x;
    int lane = threadIdx.x;
    float4 v = *(const float4*)(in + (size_t)row * EE + lane * 4);
    float s  = v.x + v.y + v.z + v.w;
    float ss = v.x*v.x + v.y*v.y + v.z*v.z + v.w*v.w;
    #pragma unroll
    for (int off = 32; off; off >>= 1) {
        s  += __shfl_xor(s,  off);
        ss += __shfl_xor(ss, off);
    }
    float mu  = s * (1.f / EE);
    float var = ss * (1.f / EE) - mu * mu;
    float rs  = rsqrtf(var + 1e-5f);
    float4 gv = *(const float4*)(g + lane * 4);
    float4 bv = *(const float4*)(b + lane * 4);
    float4 o;
    o.x = (v.x - mu) * rs * gv.x + bv.x;
    o.y = (v.y - mu) * rs * gv.y + bv.y;
    o.z = (v.z - mu) * rs * gv.z + bv.z;
    o.w = (v.w - mu) * rs * gv.w + bv.w;
    *(float4*)(out + (size_t)row * EE + lane * 4) = o;
}

// ---------------------------------------------------------------------------
// Tiled f32 GEMM: C[M,N] = act( A[M,K] @ B[K,N] + bias [+ res] )
// BM=BN=64, BK=16, 256 threads, 4x4 micro-tile per thread.
template<bool GELU_ACT, bool RES>
__global__ __launch_bounds__(256) void gemm_kernel(
    const float* __restrict__ A, const float* __restrict__ Bm,
    const float* __restrict__ bias, const float* __restrict__ res,
    float* __restrict__ C, int M, int N, int K)
{
    const int Bb = 64, BK = 16;
    __shared__ float As[16][64];
    __shared__ float Bs[16][64];
    int tid = threadIdx.x;
    int bx = blockIdx.x, by = blockIdx.y;
    int tx = tid & 15, ty = tid >> 4;

    float acc[4][4] = {};

    int arow = tid >> 2;        // 0..63  (row within A tile)
    int akq  = tid & 3;         // which float4 of the 16 k's
    int brow = tid >> 4;        // 0..15  (k within B tile)
    int bcq  = tid & 15;        // which float4 of the 64 cols

    const float* Aptr = A + (size_t)(by * Bb + arow) * K + akq * 4;
    const float* Bptr = Bm + (size_t)brow * N + bx * Bb + bcq * 4;

    for (int k0 = 0; k0 < K; k0 += BK) {
        float4 av = *(const float4*)(Aptr + k0);
        As[akq*4+0][arow] = av.x;
        As[akq*4+1][arow] = av.y;
        As[akq*4+2][arow] = av.z;
        As[akq*4+3][arow] = av.w;
        float4 bv = *(const float4*)(Bptr + (size_t)k0 * N);
        *(float4*)&Bs[brow][bcq*4] = bv;
        __syncthreads();
        #pragma unroll
        for (int k = 0; k < BK; ++k) {
            float a[4], b[4];
            #pragma unroll
            for (int i = 0; i < 4; ++i) a[i] = As[k][ty*4+i];
            #pragma unroll
            for (int j = 0; j < 4; ++j) b[j] = Bs[k][tx*4+j];
            #pragma unroll
            for (int i = 0; i < 4; ++i)
                #pragma unroll
                for (int j = 0; j < 4; ++j)
                    acc[i][j] += a[i] * b[j];
        }
        __syncthreads();
    }

    #pragma unroll
    for (int i = 0; i < 4; ++i) {
        int r  = by * Bb + ty * 4 + i;
        int c0 = bx * Bb + tx * 4;
        float4 outv;
        float* po = &outv.x;
        #pragma unroll
        for (int j = 0; j < 4; ++j) {
            float v = acc[i][j] + bias[c0 + j];
            if (RES) v += res[(size_t)r * N + c0 + j];
            if (GELU_ACT) {
                float t = v;
                v = 0.5f * t * (1.f + tanhf(0.7978845608028654f * (t + 0.044715f * t * t * t)));
            }
            po[j] = v;
        }
        *(float4*)&C[(size_t)r * N + c0] = outv;
    }
}

// ---------------------------------------------------------------------------
// Causal flash attention, f32, restructured for occupancy + ILP.
// One wave = 16 q-rows (QROWS) x 4 key-split lanes (SPLIT). KB=32 key tile in
// LDS (padded stride 36 -> conflict-free 4-row broadcast b128 reads).
// Each lane: 8 independent QK dots per tile, batched online softmax (one
// rescale per tile), then 2-step shfl_xor merge of (m,l,o) across the 4
// key-split lanes. Masked keys get s=-inf -> p=0 (== reference's -10000 path,
// which underflows to 0 in f32 softmax).
#define QROWS 16
#define KB 32
#define LPAD 36
__global__ __launch_bounds__(64, 4) void attn_kernel(
    const float* __restrict__ qkv, float* __restrict__ out)
{
    __shared__ float Ks[KB][LPAD];
    __shared__ float Vs[KB][LPAD];
    int lane = threadIdx.x;
    int qt = gridDim.x - 1 - blockIdx.x;   // heavy tiles dispatch first
    int hh = blockIdx.y, b = blockIdx.z;
    int r   = lane >> 2;                   // q-row within tile (0..15)
    int sub = lane & 3;                    // key subset (0..3)
    int qrow = qt * QROWS + r;

    const float* qptr = qkv + ((size_t)(b * SS + qrow)) * (3*EE) + hh * DD;
    float q[DD];
    #pragma unroll
    for (int d4 = 0; d4 < 8; ++d4) {
        float4 t = *(const float4*)(qptr + d4 * 4);
        q[d4*4+0] = t.x; q[d4*4+1] = t.y; q[d4*4+2] = t.z; q[d4*4+3] = t.w;
    }
    float o[DD];
    #pragma unroll
    for (int d = 0; d < DD; ++d) o[d] = 0.f;
    float m = -INFINITY, l = 0.f;
    const float scale = 0.17677669529663687f;  // 1/sqrt(32)

    int ntiles = ((qt * QROWS + (QROWS - 1)) >> 5) + 1;  // cover keys 0..qrow_max
    for (int kt = 0; kt < ntiles; ++kt) {
        int k0 = kt * KB;
        const float* kb_ = qkv + ((size_t)(b * SS + k0)) * (3*EE) + hh * DD + EE;
        const float* vb_ = kb_ + EE;
        #pragma unroll
        for (int t = 0; t < 4; ++t) {
            int idx = lane + t * 64;          // 0..255
            int row = idx >> 3, c4 = idx & 7;
            *(float4*)&Ks[row][c4*4] = *(const float4*)(kb_ + (size_t)row * (3*EE) + c4*4);
            *(float4*)&Vs[row][c4*4] = *(const float4*)(vb_ + (size_t)row * (3*EE) + c4*4);
        }
        __syncthreads();

        // 8 independent dots (keys jl = sub + 4*i)
        float s[8];
        #pragma unroll
        for (int i = 0; i < 8; ++i) {
            int jl = sub + 4*i;
            float a0 = 0.f, a1 = 0.f, a2 = 0.f, a3 = 0.f;
            #pragma unroll
            for (int d4 = 0; d4 < 8; ++d4) {
                float4 kv = *(const float4*)&Ks[jl][d4*4];
                a0 += q[d4*4+0] * kv.x;
                a1 += q[d4*4+1] * kv.y;
                a2 += q[d4*4+2] * kv.z;
                a3 += q[d4*4+3] * kv.w;
            }
            float dot = (a0 + a1) + (a2 + a3);
            s[i] = (k0 + jl <= qrow) ? dot * scale : -INFINITY;
        }
        float bmax = fmaxf(fmaxf(fmaxf(s[0], s[1]), fmaxf(s[2], s[3])),
                           fmaxf(fmaxf(s[4], s[5]), fmaxf(s[6], s[7])));
        float newm = fmaxf(m, bmax);
        float em   = fmaxf(newm, -1e37f);    // guard -inf - -inf = NaN
        float corr = __expf(m - em);
        float p[8], psum = 0.f;
        #pragma unroll
        for (int i = 0; i < 8; ++i) { p[i] = __expf(s[i] - em); psum += p[i]; }
        l = l * corr + psum;
        m = newm;
        #pragma unroll
        for (int d4 = 0; d4 < 8; ++d4) {
            float a0 = o[d4*4+0]*corr, a1 = o[d4*4+1]*corr;
            float a2 = o[d4*4+2]*corr, a3 = o[d4*4+3]*corr;
            #pragma unroll
            for (int i = 0; i < 8; ++i) {
                float4 vv = *(const float4*)&Vs[sub + 4*i][d4*4];
                a0 += p[i]*vv.x; a1 += p[i]*vv.y; a2 += p[i]*vv.z; a3 += p[i]*vv.w;
            }
            o[d4*4+0] = a0; o[d4*4+1] = a1; o[d4*4+2] = a2; o[d4*4+3] = a3;
        }
        __syncthreads();
    }

    // merge the 4 key-split partials (lanes sub=0..3) via butterfly
    #pragma unroll
    for (int off = 1; off <= 2; off <<= 1) {
        float mo = __shfl_xor(m, off);
        float lo = __shfl_xor(l, off);
        float nm = fmaxf(m, mo);
        float em = fmaxf(nm, -1e37f);
        float ca = __expf(m - em), cb = __expf(mo - em);
        l = l * ca + lo * cb;
        m = nm;
        #pragma unroll
        for (int d = 0; d < DD; ++d)
            o[d] = o[d] * ca + __shfl_xor(o[d], off) * cb;
    }

    float inv = 1.f / l;
    // after merge all 4 lanes hold the full row; lane sub writes dims [sub*8, sub*8+8)
    float* optr = out + ((size_t)(b * SS + qrow)) * EE + hh * DD + sub * 8;
    #pragma unroll
    for (int t = 0; t < 2; ++t) {
        int d0 = sub * 8 + t * 4;
        float4 w = { o[d0]*inv, o[d0+1]*inv, o[d0+2]*inv, o[d0+3]*inv };
        *(float4*)(optr + t * 4) = w;
    }
}

// ---------------------------------------------------------------------------
extern "C" void kernel_launch(void* const* d_in, const int* in_sizes, int n_in,
                              void* d_out, int out_size, void* d_ws, size_t ws_size,
                              hipStream_t stream)
{
    const int*   ids    = (const int*)  d_in[0];
    const float* wte    = (const float*)d_in[1];
    const float* wpe    = (const float*)d_in[2];
    const float* ln1_g  = (const float*)d_in[3];
    const float* ln1_b  = (const float*)d_in[4];
    const float* qkv_w  = (const float*)d_in[5];
    const float* qkv_b  = (const float*)d_in[6];
    const float* proj_w = (const float*)d_in[7];
    const float* proj_b = (const float*)d_in[8];
    const float* ln2_g  = (const float*)d_in[9];
    const float* ln2_b  = (const float*)d_in[10];
    const float* fc1_w  = (const float*)d_in[11];
    const float* fc1_b  = (const float*)d_in[12];
    const float* fc2_w  = (const float*)d_in[13];
    const float* fc2_b  = (const float*)d_in[14];
    const float* lnf_g  = (const float*)d_in[15];
    const float* lnf_b  = (const float*)d_in[16];

    float* ws    = (float*)d_ws;
    float* h     = ws;                         // 8192*256
    float* x     = h     + (size_t)NROWS*EE;   // 8192*256
    float* qkv   = x     + (size_t)NROWS*EE;   // 8192*768
    float* attno = qkv   + (size_t)NROWS*3*EE; // 8192*256
    float* m1    = attno + (size_t)NROWS*EE;   // 8192*1024

    embed_kernel<<<NROWS, 64, 0, stream>>>(ids, wte, wpe, h);

    for (int l = 0; l < LL; ++l) {
        // x = LN1(h)
        ln_kernel<<<NROWS, 64, 0, stream>>>(h, ln1_g + l*EE, ln1_b + l*EE, x);
        // qkv = x @ Wqkv + bqkv     [8192,256]@[256,768]
        gemm_kernel<false,false><<<dim3(3*EE/64, NROWS/64), 256, 0, stream>>>(
            x, qkv_w + (size_t)l*EE*3*EE, qkv_b + (size_t)l*3*EE, nullptr,
            qkv, NROWS, 3*EE, EE);
        // attno = attention(qkv)
        attn_kernel<<<dim3(SS/QROWS, HH, BB), 64, 0, stream>>>(qkv, attno);
        // h = h + attno @ Wp + bp   [8192,256]@[256,256]
        gemm_kernel<false,true><<<dim3(EE/64, NROWS/64), 256, 0, stream>>>(
            attno, proj_w + (size_t)l*EE*EE, proj_b + (size_t)l*EE, h,
            h, NROWS, EE, EE);
        // x = LN2(h)
        ln_kernel<<<NROWS, 64, 0, stream>>>(h, ln2_g + l*EE, ln2_b + l*EE, x);
        // m1 = gelu(x @ W1 + b1)    [8192,256]@[256,1024]
        gemm_kernel<true,false><<<dim3(NI/64, NROWS/64), 256, 0, stream>>>(
            x, fc1_w + (size_t)l*EE*NI, fc1_b + (size_t)l*NI, nullptr,
            m1, NROWS, NI, EE);
        // h = h + m1 @ W2 + b2      [8192,1024]@[1024,256]
        gemm_kernel<false,true><<<dim3(EE/64, NROWS/64), 256, 0, stream>>>(
            m1, fc2_w + (size_t)l*NI*EE, fc2_b + (size_t)l*EE, h,
            h, NROWS, EE, NI);
    }

    // out = LN_f(h)
    ln_kernel<<<NROWS, 64, 0, stream>>>(h, lnf_g, lnf_b, (float*)d_out);
}

// Round 4
// 1255.474 us; speedup vs baseline: 11.3540x; 11.3540x over previous
//
#include <hip/hip_runtime.h>
#include <hip/hip_bf16.h>
#include <math.h>

// Problem dims (fixed by reference)
#define BB 4
#define SS 2048
#define EE 256
#define HH 8
#define DD 32
#define LL 2
#define NI 1024
#define NROWS (BB*SS)   // 8192

// ---------------------------------------------------------------------------
__global__ __launch_bounds__(64) void embed_kernel(
    const int* __restrict__ ids, const float* __restrict__ wte,
    const float* __restrict__ wpe, float* __restrict__ h)
{
    int row  = blockIdx.x;            // b*S + s
    int s    = row & (SS - 1);
    int lane = threadIdx.x;
    int id   = ids[row];
    float4 a = *(const float4*)(wte + (size_t)id * EE + lane * 4);
    float4 p = *(const float4*)(wpe + (size_t)s  * EE + lane * 4);
    float4 o = { a.x + p.x, a.y + p.y, a.z + p.z, a.w + p.w };
    *(float4*)(h + (size_t)row * EE + lane * 4) = o;
}

// ---------------------------------------------------------------------------
__global__ __launch_bounds__(64) void ln_kernel(
    const float* __restrict__ in, const float* __restrict__ g,
    const float* __restrict__ b, float* __restrict__ out)
{
    int row  = blockIdx.x;
    int lane = threadIdx.x;
    float4 v = *(const float4*)(in + (size_t)row * EE + lane * 4);
    float s  = v.x + v.y + v.z + v.w;
    float ss = v.x*v.x + v.y*v.y + v.z*v.z + v.w*v.w;
    #pragma unroll
    for (int off = 32; off; off >>= 1) {
        s  += __shfl_xor(s,  off);
        ss += __shfl_xor(ss, off);
    }
    float mu  = s * (1.f / EE);
    float var = ss * (1.f / EE) - mu * mu;
    float rs  = rsqrtf(var + 1e-5f);
    float4 gv = *(const float4*)(g + lane * 4);
    float4 bv = *(const float4*)(b + lane * 4);
    float4 o;
    o.x = (v.x - mu) * rs * gv.x + bv.x;
    o.y = (v.y - mu) * rs * gv.y + bv.y;
    o.z = (v.z - mu) * rs * gv.z + bv.z;
    o.w = (v.w - mu) * rs * gv.w + bv.w;
    *(float4*)(out + (size_t)row * EE + lane * 4) = o;
}

// ---------------------------------------------------------------------------
// Tiled f32 GEMM: C[M,N] = act( A[M,K] @ B[K,N] + bias [+ res] )
template<bool GELU_ACT, bool RES>
__global__ __launch_bounds__(256) void gemm_kernel(
    const float* __restrict__ A, const float* __restrict__ Bm,
    const float* __restrict__ bias, const float* __restrict__ res,
    float* __restrict__ C, int M, int N, int K)
{
    const int Bb = 64, BK = 16;
    __shared__ float As[16][64];
    __shared__ float Bs[16][64];
    int tid = threadIdx.x;
    int bx = blockIdx.x, by = blockIdx.y;
    int tx = tid & 15, ty = tid >> 4;

    float acc[4][4] = {};

    int arow = tid >> 2;
    int akq  = tid & 3;
    int brow = tid >> 4;
    int bcq  = tid & 15;

    const float* Aptr = A + (size_t)(by * Bb + arow) * K + akq * 4;
    const float* Bptr = Bm + (size_t)brow * N + bx * Bb + bcq * 4;

    for (int k0 = 0; k0 < K; k0 += BK) {
        float4 av = *(const float4*)(Aptr + k0);
        As[akq*4+0][arow] = av.x;
        As[akq*4+1][arow] = av.y;
        As[akq*4+2][arow] = av.z;
        As[akq*4+3][arow] = av.w;
        float4 bv = *(const float4*)(Bptr + (size_t)k0 * N);
        *(float4*)&Bs[brow][bcq*4] = bv;
        __syncthreads();
        #pragma unroll
        for (int k = 0; k < BK; ++k) {
            float a[4], b[4];
            #pragma unroll
            for (int i = 0; i < 4; ++i) a[i] = As[k][ty*4+i];
            #pragma unroll
            for (int j = 0; j < 4; ++j) b[j] = Bs[k][tx*4+j];
            #pragma unroll
            for (int i = 0; i < 4; ++i)
                #pragma unroll
                for (int j = 0; j < 4; ++j)
                    acc[i][j] += a[i] * b[j];
        }
        __syncthreads();
    }

    #pragma unroll
    for (int i = 0; i < 4; ++i) {
        int r  = by * Bb + ty * 4 + i;
        int c0 = bx * Bb + tx * 4;
        float4 outv;
        float* po = &outv.x;
        #pragma unroll
        for (int j = 0; j < 4; ++j) {
            float v = acc[i][j] + bias[c0 + j];
            if (RES) v += res[(size_t)r * N + c0 + j];
            if (GELU_ACT) {
                float t = v;
                v = 0.5f * t * (1.f + tanhf(0.7978845608028654f * (t + 0.044715f * t * t * t)));
            }
            po[j] = v;
        }
        *(float4*)&C[(size_t)r * N + c0] = outv;
    }
}

// ---------------------------------------------------------------------------
// Causal flash attention, f32, GEMM-structured.
// Block = 256 threads, owns QB=64 q-rows of one (b,h). Per key tile (64 keys):
//   QK: 64x64 score tile, 4x4 micro-tile/thread (rows ty*4+i, cols tx*4+j),
//       Q/K tiles in LDS with XOR swizzle (c4 ^= (row>>2)&7) -> 2-way max.
//   softmax: per-row (m,l) replicated across the 16-lane row group (shfl<=8).
//   P staged via LDS (b128 row writes, broadcast column reads).
//   PV: o[4 rows][2 dims]/thread (dims tx*2..+1), V row-major pad 36.
// Per-lane state ~50 VGPR -> no scratch (the round-3 failure mode).
#define QB 64
__global__ __launch_bounds__(256) void attn_kernel(
    const float* __restrict__ qkv, float* __restrict__ out)
{
    __shared__ float Qs[QB][32];
    __shared__ float Ks[QB][32];
    __shared__ float Vs[QB][36];
    __shared__ float Ps[QB][68];

    int tid = threadIdx.x;
    int qt = gridDim.x - 1 - blockIdx.x;   // heavy tiles first
    int hh = blockIdx.y, b = blockIdx.z;
    int tx = tid & 15, ty = tid >> 4;      // ty 0..15, tx 0..15

    const float scale = 0.17677669529663687f;  // 1/sqrt(32)

    // ---- load Q tile (once), swizzled ----
    const float* qbase = qkv + ((size_t)(b * SS + qt * QB)) * (3*EE) + hh * DD;
    #pragma unroll
    for (int t = 0; t < 2; ++t) {
        int idx = tid + t * 256;       // 0..511
        int row = idx >> 3, c4 = idx & 7;
        float4 v = *(const float4*)(qbase + (size_t)row * (3*EE) + c4 * 4);
        int c4s = c4 ^ ((row >> 2) & 7);
        *(float4*)&Qs[row][c4s * 4] = v;
    }

    float s[4][4];
    float o[4][2] = {};
    float m[4] = { -INFINITY, -INFINITY, -INFINITY, -INFINITY };
    float l[4] = {};

    int ntiles = qt + 1;
    for (int kt = 0; kt < ntiles; ++kt) {
        int k0 = kt * QB;
        const float* kb = qkv + ((size_t)(b * SS + k0)) * (3*EE) + hh * DD + EE;
        const float* vb = kb + EE;

        __syncthreads();   // prev PV done before overwriting Ks/Vs
        #pragma unroll
        for (int t = 0; t < 2; ++t) {
            int idx = tid + t * 256;
            int row = idx >> 3, c4 = idx & 7;
            float4 kv = *(const float4*)(kb + (size_t)row * (3*EE) + c4 * 4);
            float4 vv = *(const float4*)(vb + (size_t)row * (3*EE) + c4 * 4);
            int c4s = c4 ^ ((row >> 2) & 7);
            *(float4*)&Ks[row][c4s * 4] = kv;
            *(float4*)&Vs[row][c4 * 4]  = vv;
        }
        __syncthreads();   // K/V (and Q on first iter) visible

        // ---- QK: 8 d4-steps, 64 FMA each ----
        #pragma unroll
        for (int i = 0; i < 4; ++i)
            #pragma unroll
            for (int j = 0; j < 4; ++j) s[i][j] = 0.f;
        #pragma unroll
        for (int d4 = 0; d4 < 8; ++d4) {
            float4 qv[4], kv[4];
            #pragma unroll
            for (int i = 0; i < 4; ++i)
                qv[i] = *(const float4*)&Qs[ty*4+i][(d4 ^ (ty & 7)) * 4];
            #pragma unroll
            for (int j = 0; j < 4; ++j)
                kv[j] = *(const float4*)&Ks[tx*4+j][(d4 ^ (tx & 7)) * 4];
            #pragma unroll
            for (int i = 0; i < 4; ++i)
                #pragma unroll
                for (int j = 0; j < 4; ++j)
                    s[i][j] += qv[i].x*kv[j].x + qv[i].y*kv[j].y
                             + qv[i].z*kv[j].z + qv[i].w*kv[j].w;
        }

        // ---- softmax (per row i; state replicated in 16-lane row group) ----
        #pragma unroll
        for (int i = 0; i < 4; ++i) {
            int qrow = qt * QB + ty * 4 + i;
            #pragma unroll
            for (int j = 0; j < 4; ++j) {
                float v = s[i][j] * scale;
                s[i][j] = (k0 + tx * 4 + j <= qrow) ? v : -INFINITY;
            }
            float bm = fmaxf(fmaxf(s[i][0], s[i][1]), fmaxf(s[i][2], s[i][3]));
            #pragma unroll
            for (int off = 1; off <= 8; off <<= 1) bm = fmaxf(bm, __shfl_xor(bm, off));
            float nm   = fmaxf(m[i], bm);
            float corr = __expf(m[i] - nm);   // exp(-inf)=0 on first tile
            m[i] = nm;
            float psum = 0.f;
            #pragma unroll
            for (int j = 0; j < 4; ++j) {
                float p = __expf(s[i][j] - nm);   // masked: exp(-inf)=0
                s[i][j] = p;
                psum += p;
            }
            #pragma unroll
            for (int off = 1; off <= 8; off <<= 1) psum += __shfl_xor(psum, off);
            l[i] = l[i] * corr + psum;
            o[i][0] *= corr;
            o[i][1] *= corr;
            // stage P row segment (b128, 2-way max)
            float4 pw = { s[i][0], s[i][1], s[i][2], s[i][3] };
            *(float4*)&Ps[ty*4+i][tx*4] = pw;
        }
        __syncthreads();   // P visible

        // ---- PV: 16 k4-steps, 32 FMA each ----
        #pragma unroll 4
        for (int k4 = 0; k4 < 16; ++k4) {
            float4 pv[4];
            #pragma unroll
            for (int i = 0; i < 4; ++i)
                pv[i] = *(const float4*)&Ps[ty*4+i][k4*4];   // broadcast (free)
            #pragma unroll
            for (int kk = 0; kk < 4; ++kk) {
                int k = k4 * 4 + kk;
                float2 vv = *(const float2*)&Vs[k][tx*2];
                float pk0 = (&pv[0].x)[kk], pk1 = (&pv[1].x)[kk];
                float pk2 = (&pv[2].x)[kk], pk3 = (&pv[3].x)[kk];
                o[0][0] += pk0 * vv.x;  o[0][1] += pk0 * vv.y;
                o[1][0] += pk1 * vv.x;  o[1][1] += pk1 * vv.y;
                o[2][0] += pk2 * vv.x;  o[2][1] += pk2 * vv.y;
                o[3][0] += pk3 * vv.x;  o[3][1] += pk3 * vv.y;
            }
        }
    }

    // ---- write out: row qrow, dims tx*2..+1 of this head ----
    #pragma unroll
    for (int i = 0; i < 4; ++i) {
        int qrow = qt * QB + ty * 4 + i;
        float inv = 1.f / l[i];
        float2 w = { o[i][0] * inv, o[i][1] * inv };
        *(float2*)(out + ((size_t)(b * SS + qrow)) * EE + hh * DD + tx * 2) = w;
    }
}

// ---------------------------------------------------------------------------
extern "C" void kernel_launch(void* const* d_in, const int* in_sizes, int n_in,
                              void* d_out, int out_size, void* d_ws, size_t ws_size,
                              hipStream_t stream)
{
    const int*   ids    = (const int*)  d_in[0];
    const float* wte    = (const float*)d_in[1];
    const float* wpe    = (const float*)d_in[2];
    const float* ln1_g  = (const float*)d_in[3];
    const float* ln1_b  = (const float*)d_in[4];
    const float* qkv_w  = (const float*)d_in[5];
    const float* qkv_b  = (const float*)d_in[6];
    const float* proj_w = (const float*)d_in[7];
    const float* proj_b = (const float*)d_in[8];
    const float* ln2_g  = (const float*)d_in[9];
    const float* ln2_b  = (const float*)d_in[10];
    const float* fc1_w  = (const float*)d_in[11];
    const float* fc1_b  = (const float*)d_in[12];
    const float* fc2_w  = (const float*)d_in[13];
    const float* fc2_b  = (const float*)d_in[14];
    const float* lnf_g  = (const float*)d_in[15];
    const float* lnf_b  = (const float*)d_in[16];

    float* ws    = (float*)d_ws;
    float* h     = ws;                         // 8192*256
    float* x     = h     + (size_t)NROWS*EE;   // 8192*256
    float* qkv   = x     + (size_t)NROWS*EE;   // 8192*768
    float* attno = qkv   + (size_t)NROWS*3*EE; // 8192*256
    float* m1    = attno + (size_t)NROWS*EE;   // 8192*1024

    embed_kernel<<<NROWS, 64, 0, stream>>>(ids, wte, wpe, h);

    for (int l = 0; l < LL; ++l) {
        ln_kernel<<<NROWS, 64, 0, stream>>>(h, ln1_g + l*EE, ln1_b + l*EE, x);
        gemm_kernel<false,false><<<dim3(3*EE/64, NROWS/64), 256, 0, stream>>>(
            x, qkv_w + (size_t)l*EE*3*EE, qkv_b + (size_t)l*3*EE, nullptr,
            qkv, NROWS, 3*EE, EE);
        attn_kernel<<<dim3(SS/QB, HH, BB), 256, 0, stream>>>(qkv, attno);
        gemm_kernel<false,true><<<dim3(EE/64, NROWS/64), 256, 0, stream>>>(
            attno, proj_w + (size_t)l*EE*EE, proj_b + (size_t)l*EE, h,
            h, NROWS, EE, EE);
        ln_kernel<<<NROWS, 64, 0, stream>>>(h, ln2_g + l*EE, ln2_b + l*EE, x);
        gemm_kernel<true,false><<<dim3(NI/64, NROWS/64), 256, 0, stream>>>(
            x, fc1_w + (size_t)l*EE*NI, fc1_b + (size_t)l*NI, nullptr,
            m1, NROWS, NI, EE);
        gemm_kernel<false,true><<<dim3(EE/64, NROWS/64), 256, 0, stream>>>(
            m1, fc2_w + (size_t)l*NI*EE, fc2_b + (size_t)l*EE, h,
            h, NROWS, EE, NI);
    }

    ln_kernel<<<NROWS, 64, 0, stream>>>(h, lnf_g, lnf_b, (float*)d_out);
}

// Round 5
// 678.592 us; speedup vs baseline: 21.0062x; 1.8501x over previous
//
#include <hip/hip_runtime.h>
#include <hip/hip_bf16.h>
#include <math.h>

// Problem dims (fixed by reference)
#define BB 4
#define SS 2048
#define EE 256
#define HH 8
#define DD 32
#define LL 2
#define NI 1024
#define NROWS (BB*SS)   // 8192

typedef float f32x4 __attribute__((ext_vector_type(4)));
typedef short s16x8 __attribute__((ext_vector_type(8)));
typedef __bf16 bf16x8 __attribute__((ext_vector_type(8)));

__device__ __forceinline__ unsigned short f2bf(float f) {
    unsigned u = __float_as_uint(f);
    u += 0x7fff + ((u >> 16) & 1);          // round-to-nearest-even
    return (unsigned short)(u >> 16);
}
__device__ __forceinline__ float bf2f(unsigned short s) {
    return __uint_as_float((unsigned)s << 16);
}
__device__ __forceinline__ f32x4 mfma16x16x32(s16x8 a, s16x8 b, f32x4 c) {
    return __builtin_amdgcn_mfma_f32_16x16x32_bf16(
        __builtin_bit_cast(bf16x8, a), __builtin_bit_cast(bf16x8, b), c, 0, 0, 0);
}

// ---------------------------------------------------------------------------
__global__ __launch_bounds__(64) void embed_kernel(
    const int* __restrict__ ids, const float* __restrict__ wte,
    const float* __restrict__ wpe, float* __restrict__ h)
{
    int row  = blockIdx.x;            // b*S + s
    int s    = row & (SS - 1);
    int lane = threadIdx.x;
    int id   = ids[row];
    float4 a = *(const float4*)(wte + (size_t)id * EE + lane * 4);
    float4 p = *(const float4*)(wpe + (size_t)s  * EE + lane * 4);
    float4 o = { a.x + p.x, a.y + p.y, a.z + p.z, a.w + p.w };
    *(float4*)(h + (size_t)row * EE + lane * 4) = o;
}

// ---------------------------------------------------------------------------
__global__ __launch_bounds__(64) void ln_kernel(
    const float* __restrict__ in, const float* __restrict__ g,
    const float* __restrict__ b, float* __restrict__ out)
{
    int row  = blockIdx.x;
    int lane = threadIdx.x;
    float4 v = *(const float4*)(in + (size_t)row * EE + lane * 4);
    float s  = v.x + v.y + v.z + v.w;
    float ss = v.x*v.x + v.y*v.y + v.z*v.z + v.w*v.w;
    #pragma unroll
    for (int off = 32; off; off >>= 1) {
        s  += __shfl_xor(s,  off);
        ss += __shfl_xor(ss, off);
    }
    float mu  = s * (1.f / EE);
    float var = ss * (1.f / EE) - mu * mu;
    float rs  = rsqrtf(var + 1e-5f);
    float4 gv = *(const float4*)(g + lane * 4);
    float4 bv = *(const float4*)(b + lane * 4);
    float4 o;
    o.x = (v.x - mu) * rs * gv.x + bv.x;
    o.y = (v.y - mu) * rs * gv.y + bv.y;
    o.z = (v.z - mu) * rs * gv.z + bv.z;
    o.w = (v.w - mu) * rs * gv.w + bv.w;
    *(float4*)(out + (size_t)row * EE + lane * 4) = o;
}

// ---------------------------------------------------------------------------
// Tiled f32 GEMM: C[M,N] = act( A[M,K] @ B[K,N] + bias [+ res] )
template<bool GELU_ACT, bool RES>
__global__ __launch_bounds__(256) void gemm_kernel(
    const float* __restrict__ A, const float* __restrict__ Bm,
    const float* __restrict__ bias, const float* __restrict__ res,
    float* __restrict__ C, int M, int N, int K)
{
    const int Bb = 64, BK = 16;
    __shared__ float As[16][64];
    __shared__ float Bs[16][64];
    int tid = threadIdx.x;
    int bx = blockIdx.x, by = blockIdx.y;
    int tx = tid & 15, ty = tid >> 4;

    float acc[4][4] = {};

    int arow = tid >> 2;
    int akq  = tid & 3;
    int brow = tid >> 4;
    int bcq  = tid & 15;

    const float* Aptr = A + (size_t)(by * Bb + arow) * K + akq * 4;
    const float* Bptr = Bm + (size_t)brow * N + bx * Bb + bcq * 4;

    for (int k0 = 0; k0 < K; k0 += BK) {
        float4 av = *(const float4*)(Aptr + k0);
        As[akq*4+0][arow] = av.x;
        As[akq*4+1][arow] = av.y;
        As[akq*4+2][arow] = av.z;
        As[akq*4+3][arow] = av.w;
        float4 bv = *(const float4*)(Bptr + (size_t)k0 * N);
        *(float4*)&Bs[brow][bcq*4] = bv;
        __syncthreads();
        #pragma unroll
        for (int k = 0; k < BK; ++k) {
            float a[4], b[4];
            #pragma unroll
            for (int i = 0; i < 4; ++i) a[i] = As[k][ty*4+i];
            #pragma unroll
            for (int j = 0; j < 4; ++j) b[j] = Bs[k][tx*4+j];
            #pragma unroll
            for (int i = 0; i < 4; ++i)
                #pragma unroll
                for (int j = 0; j < 4; ++j)
                    acc[i][j] += a[i] * b[j];
        }
        __syncthreads();
    }

    #pragma unroll
    for (int i = 0; i < 4; ++i) {
        int r  = by * Bb + ty * 4 + i;
        int c0 = bx * Bb + tx * 4;
        float4 outv;
        float* po = &outv.x;
        #pragma unroll
        for (int j = 0; j < 4; ++j) {
            float v = acc[i][j] + bias[c0 + j];
            if (RES) v += res[(size_t)r * N + c0 + j];
            if (GELU_ACT) {
                float t = v;
                v = 0.5f * t * (1.f + tanhf(0.7978845608028654f * (t + 0.044715f * t * t * t)));
            }
            po[j] = v;
        }
        *(float4*)&C[(size_t)r * N + c0] = outv;
    }
}

// ---------------------------------------------------------------------------
// Causal flash attention via bf16 MFMA (16x16x32), f32 softmax/accumulators.
// Block = 256 threads = 4 waves; block owns 64 q-rows of one (b,h); wave w
// owns rows w*16..w*16+15. Per 64-key tile:
//   QK: S[16q x 64k] = 4 mfma. A-frag = Q (loaded once: lane holds
//       Q[row=c][h*8+j]). B-frag g = Ks[g*16+c][h*8..+7] (bf16 LDS rows).
//   acc layout (m89-verified): lane holds S[h*4+r][g*16+c].
//   softmax per row r: in-lane max/sum over g + shfl_xor{1,2,4,8} over c.
//   P: written bf16 to per-wave Ps[16][64] (S-layout), re-read as A-frags
//       (lane: Ps[c][kc*32+h*8..+7]); l-sum uses bf16-rounded P for
//       consistency with PV.
//   PV: O[16q x 32d] += P(16x64) x V(64x32) = 2kc x 2dc mfma; V staged
//       TRANSPOSED (Vt[d][key] bf16) so B-frags are row reads.
// LDS strides (shorts): Ks 40, Vt 88, Ps 72 -> b128 bank-group indices
// (5c+h)%8, (11c+h)%8, (c+h)%8 all uniform over the wave -> conflict-free.
// Total LDS 19.5 KB.
#define QB 64
#define KSTR 40
#define VSTR 88
#define PSTR 72
__global__ __launch_bounds__(256) void attn_kernel(
    const float* __restrict__ qkv, float* __restrict__ out)
{
    __shared__ __align__(16) unsigned short Ks[QB][KSTR];
    __shared__ __align__(16) unsigned short Vt[DD][VSTR];
    __shared__ __align__(16) unsigned short Ps[4][16][PSTR];

    int tid  = threadIdx.x;
    int qt   = gridDim.x - 1 - blockIdx.x;   // heavy tiles first
    int hh   = blockIdx.y, b = blockIdx.z;
    int wid  = tid >> 6, lane = tid & 63;
    int h    = lane >> 4, c = lane & 15;

    const float scale = 0.17677669529663687f;  // 1/sqrt(32)

    // ---- Q A-frag (once): lane holds Q[row=c][h*8+j] ----
    int qfrow = qt * QB + wid * 16 + c;
    const float* qp = qkv + ((size_t)(b * SS + qfrow)) * (3*EE) + hh * DD + h * 8;
    s16x8 qfrag;
    {
        float4 q0 = *(const float4*)(qp);
        float4 q1 = *(const float4*)(qp + 4);
        qfrag[0] = (short)f2bf(q0.x); qfrag[1] = (short)f2bf(q0.y);
        qfrag[2] = (short)f2bf(q0.z); qfrag[3] = (short)f2bf(q0.w);
        qfrag[4] = (short)f2bf(q1.x); qfrag[5] = (short)f2bf(q1.y);
        qfrag[6] = (short)f2bf(q1.z); qfrag[7] = (short)f2bf(q1.w);
    }

    f32x4 o0 = {0.f,0.f,0.f,0.f}, o1 = {0.f,0.f,0.f,0.f};
    float m[4] = { -INFINITY, -INFINITY, -INFINITY, -INFINITY };
    float l[4] = { 0.f, 0.f, 0.f, 0.f };

    int srow = tid >> 2, scq = tid & 3;      // staging: row 0..63, chunk 0..3
    int ntiles = qt + 1;
    for (int kt = 0; kt < ntiles; ++kt) {
        int k0 = kt * QB;
        const float* kb = qkv + ((size_t)(b * SS + k0)) * (3*EE) + hh * DD + EE;
        const float* vb = kb + EE;

        __syncthreads();   // prev tile's K/V reads done
        {
            const float* kr = kb + (size_t)srow * (3*EE) + scq * 8;
            float4 ka = *(const float4*)kr;
            float4 kb4 = *(const float4*)(kr + 4);
            s16x8 kv;
            kv[0]=(short)f2bf(ka.x);  kv[1]=(short)f2bf(ka.y);
            kv[2]=(short)f2bf(ka.z);  kv[3]=(short)f2bf(ka.w);
            kv[4]=(short)f2bf(kb4.x); kv[5]=(short)f2bf(kb4.y);
            kv[6]=(short)f2bf(kb4.z); kv[7]=(short)f2bf(kb4.w);
            *(s16x8*)&Ks[srow][scq * 8] = kv;
            const float* vr = vb + (size_t)srow * (3*EE) + scq * 8;
            float4 va = *(const float4*)vr;
            float4 vb4 = *(const float4*)(vr + 4);
            int d0 = scq * 8;
            Vt[d0+0][srow] = f2bf(va.x);  Vt[d0+1][srow] = f2bf(va.y);
            Vt[d0+2][srow] = f2bf(va.z);  Vt[d0+3][srow] = f2bf(va.w);
            Vt[d0+4][srow] = f2bf(vb4.x); Vt[d0+5][srow] = f2bf(vb4.y);
            Vt[d0+6][srow] = f2bf(vb4.z); Vt[d0+7][srow] = f2bf(vb4.w);
        }
        __syncthreads();   // K/V visible

        // ---- QK: 4 mfmas over key groups ----
        f32x4 sg[4];
        #pragma unroll
        for (int g = 0; g < 4; ++g) {
            s16x8 kf = *(const s16x8*)&Ks[g * 16 + c][h * 8];
            f32x4 z = {0.f,0.f,0.f,0.f};
            sg[g] = mfma16x16x32(qfrag, kf, z);
        }

        // ---- softmax rows R = h*4+r ----
        #pragma unroll
        for (int r = 0; r < 4; ++r) {
            int qrow = qt * QB + wid * 16 + h * 4 + r;
            float sv[4];
            #pragma unroll
            for (int g = 0; g < 4; ++g) {
                float v = sg[g][r] * scale;
                sv[g] = (k0 + g * 16 + c <= qrow) ? v : -INFINITY;
            }
            float bm = fmaxf(fmaxf(sv[0], sv[1]), fmaxf(sv[2], sv[3]));
            #pragma unroll
            for (int off = 1; off <= 8; off <<= 1) bm = fmaxf(bm, __shfl_xor(bm, off));
            float nm   = fmaxf(m[r], bm);
            float corr = __expf(m[r] - nm);     // exp(-inf)=0 on first tile
            m[r] = nm;
            float psum = 0.f;
            #pragma unroll
            for (int g = 0; g < 4; ++g) {
                unsigned short pb = f2bf(__expf(sv[g] - nm));  // masked: exp(-inf)=0
                Ps[wid][h * 4 + r][g * 16 + c] = pb;
                psum += bf2f(pb);               // l consistent with bf16 P used in PV
            }
            #pragma unroll
            for (int off = 1; off <= 8; off <<= 1) psum += __shfl_xor(psum, off);
            l[r] = l[r] * corr + psum;
            o0[r] *= corr;
            o1[r] *= corr;
        }

        // ---- PV: 2 kc x 2 dc mfmas (same-wave Ps RAW: in-order LDS) ----
        #pragma unroll
        for (int kc = 0; kc < 2; ++kc) {
            s16x8 pf = *(const s16x8*)&Ps[wid][c][kc * 32 + h * 8];
            s16x8 v0 = *(const s16x8*)&Vt[c][kc * 32 + h * 8];
            s16x8 v1 = *(const s16x8*)&Vt[16 + c][kc * 32 + h * 8];
            o0 = mfma16x16x32(pf, v0, o0);
            o1 = mfma16x16x32(pf, v1, o1);
        }
    }

    // ---- write out ----
    #pragma unroll
    for (int r = 0; r < 4; ++r) {
        int qrow = qt * QB + wid * 16 + h * 4 + r;
        float inv = 1.f / l[r];
        float* op = out + ((size_t)(b * SS + qrow)) * EE + hh * DD;
        op[c]      = o0[r] * inv;
        op[16 + c] = o1[r] * inv;
    }
}

// ---------------------------------------------------------------------------
extern "C" void kernel_launch(void* const* d_in, const int* in_sizes, int n_in,
                              void* d_out, int out_size, void* d_ws, size_t ws_size,
                              hipStream_t stream)
{
    const int*   ids    = (const int*)  d_in[0];
    const float* wte    = (const float*)d_in[1];
    const float* wpe    = (const float*)d_in[2];
    const float* ln1_g  = (const float*)d_in[3];
    const float* ln1_b  = (const float*)d_in[4];
    const float* qkv_w  = (const float*)d_in[5];
    const float* qkv_b  = (const float*)d_in[6];
    const float* proj_w = (const float*)d_in[7];
    const float* proj_b = (const float*)d_in[8];
    const float* ln2_g  = (const float*)d_in[9];
    const float* ln2_b  = (const float*)d_in[10];
    const float* fc1_w  = (const float*)d_in[11];
    const float* fc1_b  = (const float*)d_in[12];
    const float* fc2_w  = (const float*)d_in[13];
    const float* fc2_b  = (const float*)d_in[14];
    const float* lnf_g  = (const float*)d_in[15];
    const float* lnf_b  = (const float*)d_in[16];

    float* ws    = (float*)d_ws;
    float* h     = ws;                         // 8192*256
    float* x     = h     + (size_t)NROWS*EE;   // 8192*256
    float* qkv   = x     + (size_t)NROWS*EE;   // 8192*768
    float* attno = qkv   + (size_t)NROWS*3*EE; // 8192*256
    float* m1    = attno + (size_t)NROWS*EE;   // 8192*1024

    embed_kernel<<<NROWS, 64, 0, stream>>>(ids, wte, wpe, h);

    for (int l = 0; l < LL; ++l) {
        ln_kernel<<<NROWS, 64, 0, stream>>>(h, ln1_g + l*EE, ln1_b + l*EE, x);
        gemm_kernel<false,false><<<dim3(3*EE/64, NROWS/64), 256, 0, stream>>>(
            x, qkv_w + (size_t)l*EE*3*EE, qkv_b + (size_t)l*3*EE, nullptr,
            qkv, NROWS, 3*EE, EE);
        attn_kernel<<<dim3(SS/QB, HH, BB), 256, 0, stream>>>(qkv, attno);
        gemm_kernel<false,true><<<dim3(EE/64, NROWS/64), 256, 0, stream>>>(
            attno, proj_w + (size_t)l*EE*EE, proj_b + (size_t)l*EE, h,
            h, NROWS, EE, EE);
        ln_kernel<<<NROWS, 64, 0, stream>>>(h, ln2_g + l*EE, ln2_b + l*EE, x);
        gemm_kernel<true,false><<<dim3(NI/64, NROWS/64), 256, 0, stream>>>(
            x, fc1_w + (size_t)l*EE*NI, fc1_b + (size_t)l*NI, nullptr,
            m1, NROWS, NI, EE);
        gemm_kernel<false,true><<<dim3(EE/64, NROWS/64), 256, 0, stream>>>(
            m1, fc2_w + (size_t)l*NI*EE, fc2_b + (size_t)l*EE, h,
            h, NROWS, EE, NI);
    }

    ln_kernel<<<NROWS, 64, 0, stream>>>(h, lnf_g, lnf_b, (float*)d_out);
}

// Round 6
// 378.416 us; speedup vs baseline: 37.6692x; 1.7932x over previous
//
#include <hip/hip_runtime.h>
#include <hip/hip_bf16.h>
#include <math.h>

// Problem dims (fixed by reference)
#define BB 4
#define SS 2048
#define EE 256
#define HH 8
#define DD 32
#define LL 2
#define NI 1024
#define NROWS (BB*SS)   // 8192

typedef float f32x4 __attribute__((ext_vector_type(4)));
typedef short s16x8 __attribute__((ext_vector_type(8)));
typedef __bf16 bf16x8 __attribute__((ext_vector_type(8)));
typedef unsigned short ushort_t;

__device__ __forceinline__ unsigned short f2bf(float f) {
    unsigned u = __float_as_uint(f);
    u += 0x7fff + ((u >> 16) & 1);          // round-to-nearest-even
    return (unsigned short)(u >> 16);
}
__device__ __forceinline__ float bf2f(unsigned short s) {
    return __uint_as_float((unsigned)s << 16);
}
__device__ __forceinline__ f32x4 mfma16x16x32(s16x8 a, s16x8 b, f32x4 c) {
    return __builtin_amdgcn_mfma_f32_16x16x32_bf16(
        __builtin_bit_cast(bf16x8, a), __builtin_bit_cast(bf16x8, b), c, 0, 0, 0);
}

// ---------------------------------------------------------------------------
__global__ __launch_bounds__(64) void embed_kernel(
    const int* __restrict__ ids, const float* __restrict__ wte,
    const float* __restrict__ wpe, float* __restrict__ h)
{
    int row  = blockIdx.x;            // b*S + s
    int s    = row & (SS - 1);
    int lane = threadIdx.x;
    int id   = ids[row];
    float4 a = *(const float4*)(wte + (size_t)id * EE + lane * 4);
    float4 p = *(const float4*)(wpe + (size_t)s  * EE + lane * 4);
    float4 o = { a.x + p.x, a.y + p.y, a.z + p.z, a.w + p.w };
    *(float4*)(h + (size_t)row * EE + lane * 4) = o;
}

// ---------------------------------------------------------------------------
// LayerNorm over E=256; OUTBF selects bf16 (activations) vs f32 (final out).
template<bool OUTBF>
__global__ __launch_bounds__(64) void ln_kernel(
    const float* __restrict__ in, const float* __restrict__ g,
    const float* __restrict__ b, void* __restrict__ out)
{
    int row  = blockIdx.x;
    int lane = threadIdx.x;
    float4 v = *(const float4*)(in + (size_t)row * EE + lane * 4);
    float s  = v.x + v.y + v.z + v.w;
    float ss = v.x*v.x + v.y*v.y + v.z*v.z + v.w*v.w;
    #pragma unroll
    for (int off = 32; off; off >>= 1) {
        s  += __shfl_xor(s,  off);
        ss += __shfl_xor(ss, off);
    }
    float mu  = s * (1.f / EE);
    float var = ss * (1.f / EE) - mu * mu;
    float rs  = rsqrtf(var + 1e-5f);
    float4 gv = *(const float4*)(g + lane * 4);
    float4 bv = *(const float4*)(b + lane * 4);
    float4 o;
    o.x = (v.x - mu) * rs * gv.x + bv.x;
    o.y = (v.y - mu) * rs * gv.y + bv.y;
    o.z = (v.z - mu) * rs * gv.z + bv.z;
    o.w = (v.w - mu) * rs * gv.w + bv.w;
    if (OUTBF) {
        ushort4 w = { f2bf(o.x), f2bf(o.y), f2bf(o.z), f2bf(o.w) };
        *(ushort4*)((ushort_t*)out + (size_t)row * EE + lane * 4) = w;
    } else {
        *(float4*)((float*)out + (size_t)row * EE + lane * 4) = o;
    }
}

// ---------------------------------------------------------------------------
// Weight transpose+convert: W[K,N] f32 -> Wt[N,K] bf16. Grid (N/32, K/32).
__global__ __launch_bounds__(256) void wconv_kernel(
    const float* __restrict__ W, ushort_t* __restrict__ Wt, int K, int N)
{
    __shared__ float t[32][33];
    int n0 = blockIdx.x * 32, k0 = blockIdx.y * 32;
    int tx = threadIdx.x & 31, ty = threadIdx.x >> 5;   // ty 0..7
    #pragma unroll
    for (int i = 0; i < 4; ++i) {
        int k = ty + i * 8;
        t[k][tx] = W[(size_t)(k0 + k) * N + n0 + tx];
    }
    __syncthreads();
    #pragma unroll
    for (int i = 0; i < 4; ++i) {
        int n = ty + i * 8;
        Wt[(size_t)(n0 + n) * K + k0 + tx] = f2bf(t[tx][n]);
    }
}

// ---------------------------------------------------------------------------
// bf16 MFMA GEMM: C[M,N] = act( A[M,K] @ Wt[N,K]^T + bias [+ res] )
// BM=128, BN=64, BK=32; 256 threads = 4 waves; wave tile 32x64 (2x4 frags of
// 16x16x32). A,Wt bf16; accum f32; C f32 or bf16. LDS stride-40 pad (same
// bank pattern validated in attn). 2 barriers/K-step (m97-class structure).
template<bool OUT_BF, bool GELU_ACT, bool RES>
__global__ __launch_bounds__(256) void gemm_bf(
    const ushort_t* __restrict__ A, const ushort_t* __restrict__ Bt,
    const float* __restrict__ bias, const float* __restrict__ res,
    void* __restrict__ C, int M, int N, int K)
{
    __shared__ __align__(16) ushort_t As[128][40];
    __shared__ __align__(16) ushort_t Bs[64][40];
    int tid = threadIdx.x;
    int wid = tid >> 6, lane = tid & 63;
    int h = lane >> 4, c = lane & 15;
    int bx = blockIdx.x, by = blockIdx.y;

    f32x4 acc[2][4] = {};

    int arow = tid >> 2, ac = tid & 3;   // staging row 0..63, 16B chunk 0..3
    const ushort_t* Ap = A  + (size_t)(by * 128 + arow) * K + ac * 8;
    const ushort_t* Bp = Bt + (size_t)(bx * 64  + arow) * K + ac * 8;

    for (int k0 = 0; k0 < K; k0 += 32) {
        s16x8 a0 = *(const s16x8*)(Ap + k0);
        s16x8 a1 = *(const s16x8*)(Ap + (size_t)64 * K + k0);
        s16x8 b0 = *(const s16x8*)(Bp + k0);
        __syncthreads();                 // prior mfma reads done
        *(s16x8*)&As[arow][ac * 8]      = a0;
        *(s16x8*)&As[64 + arow][ac * 8] = a1;
        *(s16x8*)&Bs[arow][ac * 8]      = b0;
        __syncthreads();                 // tiles visible

        s16x8 af[2], bf[4];
        #pragma unroll
        for (int i = 0; i < 2; ++i)
            af[i] = *(const s16x8*)&As[wid * 32 + i * 16 + c][h * 8];
        #pragma unroll
        for (int j = 0; j < 4; ++j)
            bf[j] = *(const s16x8*)&Bs[j * 16 + c][h * 8];
        #pragma unroll
        for (int i = 0; i < 2; ++i)
            #pragma unroll
            for (int j = 0; j < 4; ++j)
                acc[i][j] = mfma16x16x32(af[i], bf[j], acc[i][j]);
    }

    // epilogue: lane holds C[row=by*128+wid*32+i*16+h*4+r][col=bx*64+j*16+c]
    float bj[4];
    #pragma unroll
    for (int j = 0; j < 4; ++j) bj[j] = bias[bx * 64 + j * 16 + c];
    #pragma unroll
    for (int i = 0; i < 2; ++i) {
        #pragma unroll
        for (int r = 0; r < 4; ++r) {
            int row = by * 128 + wid * 32 + i * 16 + h * 4 + r;
            #pragma unroll
            for (int j = 0; j < 4; ++j) {
                int col = bx * 64 + j * 16 + c;
                float v = acc[i][j][r] + bj[j];
                if (RES) v += res[(size_t)row * N + col];
                if (GELU_ACT) {
                    float t = v;
                    v = 0.5f * t * (1.f + tanhf(0.7978845608028654f *
                                                (t + 0.044715f * t * t * t)));
                }
                if (OUT_BF) ((ushort_t*)C)[(size_t)row * N + col] = f2bf(v);
                else        ((float*)C)[(size_t)row * N + col]    = v;
            }
        }
    }
}

// ---------------------------------------------------------------------------
// Causal flash attention via bf16 MFMA; qkv input and attno output are bf16.
// Structure identical to round 5 (validated), minus all f2bf staging work.
#define QB 64
#define KSTR 40
#define VSTR 88
#define PSTR 72
__global__ __launch_bounds__(256) void attn_kernel(
    const ushort_t* __restrict__ qkv, ushort_t* __restrict__ out)
{
    __shared__ __align__(16) ushort_t Ks[QB][KSTR];
    __shared__ __align__(16) ushort_t Vt[DD][VSTR];
    __shared__ __align__(16) ushort_t Ps[4][16][PSTR];

    int tid  = threadIdx.x;
    int qt   = gridDim.x - 1 - blockIdx.x;   // heavy tiles first
    int hh   = blockIdx.y, b = blockIdx.z;
    int wid  = tid >> 6, lane = tid & 63;
    int h    = lane >> 4, c = lane & 15;

    const float scale = 0.17677669529663687f;  // 1/sqrt(32)

    // Q A-frag: lane holds Q[row=c][h*8+j]
    int qfrow = qt * QB + wid * 16 + c;
    s16x8 qfrag = *(const s16x8*)(qkv + ((size_t)(b * SS + qfrow)) * (3*EE)
                                  + hh * DD + h * 8);

    f32x4 o0 = {0.f,0.f,0.f,0.f}, o1 = {0.f,0.f,0.f,0.f};
    float m[4] = { -INFINITY, -INFINITY, -INFINITY, -INFINITY };
    float l[4] = { 0.f, 0.f, 0.f, 0.f };

    int srow = tid >> 2, scq = tid & 3;
    int ntiles = qt + 1;
    for (int kt = 0; kt < ntiles; ++kt) {
        int k0 = kt * QB;
        const ushort_t* kb = qkv + ((size_t)(b * SS + k0)) * (3*EE) + hh * DD + EE;
        const ushort_t* vb = kb + EE;

        __syncthreads();
        {
            s16x8 kv = *(const s16x8*)(kb + (size_t)srow * (3*EE) + scq * 8);
            *(s16x8*)&Ks[srow][scq * 8] = kv;
            s16x8 vv = *(const s16x8*)(vb + (size_t)srow * (3*EE) + scq * 8);
            int d0 = scq * 8;
            #pragma unroll
            for (int j = 0; j < 8; ++j) Vt[d0 + j][srow] = (ushort_t)vv[j];
        }
        __syncthreads();

        // QK: 4 mfmas
        f32x4 sg[4];
        #pragma unroll
        for (int g = 0; g < 4; ++g) {
            s16x8 kf = *(const s16x8*)&Ks[g * 16 + c][h * 8];
            f32x4 z = {0.f,0.f,0.f,0.f};
            sg[g] = mfma16x16x32(qfrag, kf, z);
        }

        // softmax rows R = h*4+r
        #pragma unroll
        for (int r = 0; r < 4; ++r) {
            int qrow = qt * QB + wid * 16 + h * 4 + r;
            float sv[4];
            #pragma unroll
            for (int g = 0; g < 4; ++g) {
                float v = sg[g][r] * scale;
                sv[g] = (k0 + g * 16 + c <= qrow) ? v : -INFINITY;
            }
            float bm = fmaxf(fmaxf(sv[0], sv[1]), fmaxf(sv[2], sv[3]));
            #pragma unroll
            for (int off = 1; off <= 8; off <<= 1) bm = fmaxf(bm, __shfl_xor(bm, off));
            float nm   = fmaxf(m[r], bm);
            float corr = __expf(m[r] - nm);
            m[r] = nm;
            float psum = 0.f;
            #pragma unroll
            for (int g = 0; g < 4; ++g) {
                unsigned short pb = f2bf(__expf(sv[g] - nm));
                Ps[wid][h * 4 + r][g * 16 + c] = pb;
                psum += bf2f(pb);
            }
            #pragma unroll
            for (int off = 1; off <= 8; off <<= 1) psum += __shfl_xor(psum, off);
            l[r] = l[r] * corr + psum;
            o0[r] *= corr;
            o1[r] *= corr;
        }

        // PV: 2 kc x 2 dc mfmas
        #pragma unroll
        for (int kc = 0; kc < 2; ++kc) {
            s16x8 pf = *(const s16x8*)&Ps[wid][c][kc * 32 + h * 8];
            s16x8 v0 = *(const s16x8*)&Vt[c][kc * 32 + h * 8];
            s16x8 v1 = *(const s16x8*)&Vt[16 + c][kc * 32 + h * 8];
            o0 = mfma16x16x32(pf, v0, o0);
            o1 = mfma16x16x32(pf, v1, o1);
        }
    }

    // write out (bf16)
    #pragma unroll
    for (int r = 0; r < 4; ++r) {
        int qrow = qt * QB + wid * 16 + h * 4 + r;
        float inv = 1.f / l[r];
        ushort_t* op = out + ((size_t)(b * SS + qrow)) * EE + hh * DD;
        op[c]      = f2bf(o0[r] * inv);
        op[16 + c] = f2bf(o1[r] * inv);
    }
}

// ---------------------------------------------------------------------------
extern "C" void kernel_launch(void* const* d_in, const int* in_sizes, int n_in,
                              void* d_out, int out_size, void* d_ws, size_t ws_size,
                              hipStream_t stream)
{
    const int*   ids    = (const int*)  d_in[0];
    const float* wte    = (const float*)d_in[1];
    const float* wpe    = (const float*)d_in[2];
    const float* ln1_g  = (const float*)d_in[3];
    const float* ln1_b  = (const float*)d_in[4];
    const float* qkv_w  = (const float*)d_in[5];
    const float* qkv_b  = (const float*)d_in[6];
    const float* proj_w = (const float*)d_in[7];
    const float* proj_b = (const float*)d_in[8];
    const float* ln2_g  = (const float*)d_in[9];
    const float* ln2_b  = (const float*)d_in[10];
    const float* fc1_w  = (const float*)d_in[11];
    const float* fc1_b  = (const float*)d_in[12];
    const float* fc2_w  = (const float*)d_in[13];
    const float* fc2_b  = (const float*)d_in[14];
    const float* lnf_g  = (const float*)d_in[15];
    const float* lnf_b  = (const float*)d_in[16];

    float*    h        = (float*)d_ws;                         // 8192*256 f32
    ushort_t* x_bf     = (ushort_t*)(h + (size_t)NROWS*EE);    // 8192*256
    ushort_t* qkv_bf   = x_bf   + (size_t)NROWS*EE;            // 8192*768
    ushort_t* attno_bf = qkv_bf + (size_t)NROWS*3*EE;          // 8192*256
    ushort_t* m1_bf    = attno_bf + (size_t)NROWS*EE;          // 8192*1024
    ushort_t* wq_t     = m1_bf  + (size_t)NROWS*NI;            // [2][768][256]
    ushort_t* wp_t     = wq_t   + (size_t)2*3*EE*EE;           // [2][256][256]
    ushort_t* w1_t     = wp_t   + (size_t)2*EE*EE;             // [2][1024][256]
    ushort_t* w2_t     = w1_t   + (size_t)2*EE*NI;             // [2][256][1024]

    // one-time (per call) weight transpose+convert
    for (int l = 0; l < LL; ++l) {
        wconv_kernel<<<dim3(3*EE/32, EE/32), 256, 0, stream>>>(
            qkv_w + (size_t)l*EE*3*EE, wq_t + (size_t)l*3*EE*EE, EE, 3*EE);
        wconv_kernel<<<dim3(EE/32, EE/32), 256, 0, stream>>>(
            proj_w + (size_t)l*EE*EE, wp_t + (size_t)l*EE*EE, EE, EE);
        wconv_kernel<<<dim3(NI/32, EE/32), 256, 0, stream>>>(
            fc1_w + (size_t)l*EE*NI, w1_t + (size_t)l*EE*NI, EE, NI);
        wconv_kernel<<<dim3(EE/32, NI/32), 256, 0, stream>>>(
            fc2_w + (size_t)l*NI*EE, w2_t + (size_t)l*NI*EE, NI, EE);
    }

    embed_kernel<<<NROWS, 64, 0, stream>>>(ids, wte, wpe, h);

    for (int l = 0; l < LL; ++l) {
        ln_kernel<true><<<NROWS, 64, 0, stream>>>(h, ln1_g + l*EE, ln1_b + l*EE, x_bf);
        gemm_bf<true,false,false><<<dim3(3*EE/64, NROWS/128), 256, 0, stream>>>(
            x_bf, wq_t + (size_t)l*3*EE*EE, qkv_b + (size_t)l*3*EE, nullptr,
            qkv_bf, NROWS, 3*EE, EE);
        attn_kernel<<<dim3(SS/QB, HH, BB), 256, 0, stream>>>(qkv_bf, attno_bf);
        gemm_bf<false,false,true><<<dim3(EE/64, NROWS/128), 256, 0, stream>>>(
            attno_bf, wp_t + (size_t)l*EE*EE, proj_b + (size_t)l*EE, h,
            h, NROWS, EE, EE);
        ln_kernel<true><<<NROWS, 64, 0, stream>>>(h, ln2_g + l*EE, ln2_b + l*EE, x_bf);
        gemm_bf<true,true,false><<<dim3(NI/64, NROWS/128), 256, 0, stream>>>(
            x_bf, w1_t + (size_t)l*EE*NI, fc1_b + (size_t)l*NI, nullptr,
            m1_bf, NROWS, NI, EE);
        gemm_bf<false,false,true><<<dim3(EE/64, NROWS/128), 256, 0, stream>>>(
            m1_bf, w2_t + (size_t)l*NI*EE, fc2_b + (size_t)l*EE, h,
            h, NROWS, EE, NI);
    }

    ln_kernel<false><<<NROWS, 64, 0, stream>>>(h, lnf_g, lnf_b, (float*)d_out);
}

// Round 8
// 307.073 us; speedup vs baseline: 46.4210x; 1.2323x over previous
//
#include <hip/hip_runtime.h>
#include <hip/hip_bf16.h>
#include <math.h>

// Problem dims (fixed by reference)
#define BB 4
#define SS 2048
#define EE 256
#define HH 8
#define DD 32
#define LL 2
#define NI 1024
#define NROWS (BB*SS)   // 8192
#define NRL   (BB*HH*SS) // 65536 flat (b,h,s) rows

typedef float f32x4 __attribute__((ext_vector_type(4)));
typedef short s16x8 __attribute__((ext_vector_type(8)));
typedef __bf16 bf16x8 __attribute__((ext_vector_type(8)));
typedef unsigned short ushort_t;

__device__ __forceinline__ unsigned short f2bf(float f) {
    unsigned u = __float_as_uint(f);
    u += 0x7fff + ((u >> 16) & 1);          // round-to-nearest-even
    return (unsigned short)(u >> 16);
}
__device__ __forceinline__ float bf2f(unsigned short s) {
    return __uint_as_float((unsigned)s << 16);
}
__device__ __forceinline__ f32x4 mfma16x16x32(s16x8 a, s16x8 b, f32x4 c) {
    return __builtin_amdgcn_mfma_f32_16x16x32_bf16(
        __builtin_bit_cast(bf16x8, a), __builtin_bit_cast(bf16x8, b), c, 0, 0, 0);
}

// ---------------------------------------------------------------------------
// Embedding, 4 rows per 256-thread block (wave per row).
__global__ __launch_bounds__(256) void embed_kernel(
    const int* __restrict__ ids, const float* __restrict__ wte,
    const float* __restrict__ wpe, float* __restrict__ h)
{
    int row  = blockIdx.x * 4 + (threadIdx.x >> 6);
    int s    = row & (SS - 1);
    int lane = threadIdx.x & 63;
    int id   = ids[row];
    float4 a = *(const float4*)(wte + (size_t)id * EE + lane * 4);
    float4 p = *(const float4*)(wpe + (size_t)s  * EE + lane * 4);
    float4 o = { a.x + p.x, a.y + p.y, a.z + p.z, a.w + p.w };
    *(float4*)(h + (size_t)row * EE + lane * 4) = o;
}

// ---------------------------------------------------------------------------
// LayerNorm over E=256; 4 rows per 256-thread block (wave per row).
template<bool OUTBF>
__global__ __launch_bounds__(256) void ln_kernel(
    const float* __restrict__ in, const float* __restrict__ g,
    const float* __restrict__ b, void* __restrict__ out)
{
    int row  = blockIdx.x * 4 + (threadIdx.x >> 6);
    int lane = threadIdx.x & 63;
    float4 v = *(const float4*)(in + (size_t)row * EE + lane * 4);
    float s  = v.x + v.y + v.z + v.w;
    float ss = v.x*v.x + v.y*v.y + v.z*v.z + v.w*v.w;
    #pragma unroll
    for (int off = 32; off; off >>= 1) {
        s  += __shfl_xor(s,  off);
        ss += __shfl_xor(ss, off);
    }
    float mu  = s * (1.f / EE);
    float var = ss * (1.f / EE) - mu * mu;
    float rs  = rsqrtf(var + 1e-5f);
    float4 gv = *(const float4*)(g + lane * 4);
    float4 bv = *(const float4*)(b + lane * 4);
    float4 o;
    o.x = (v.x - mu) * rs * gv.x + bv.x;
    o.y = (v.y - mu) * rs * gv.y + bv.y;
    o.z = (v.z - mu) * rs * gv.z + bv.z;
    o.w = (v.w - mu) * rs * gv.w + bv.w;
    if (OUTBF) {
        ushort4 w = { f2bf(o.x), f2bf(o.y), f2bf(o.z), f2bf(o.w) };
        *(ushort4*)((ushort_t*)out + (size_t)row * EE + lane * 4) = w;
    } else {
        *(float4*)((float*)out + (size_t)row * EE + lane * 4) = o;
    }
}

// ---------------------------------------------------------------------------
// Weight transpose+convert: W[K,N] f32 -> Wt[N,K] bf16. Grid (N/32, K/32).
__global__ __launch_bounds__(256) void wconv_kernel(
    const float* __restrict__ W, ushort_t* __restrict__ Wt, int K, int N)
{
    __shared__ float t[32][33];
    int n0 = blockIdx.x * 32, k0 = blockIdx.y * 32;
    int tx = threadIdx.x & 31, ty = threadIdx.x >> 5;   // ty 0..7
    #pragma unroll
    for (int i = 0; i < 4; ++i) {
        int k = ty + i * 8;
        t[k][tx] = W[(size_t)(k0 + k) * N + n0 + tx];
    }
    __syncthreads();
    #pragma unroll
    for (int i = 0; i < 4; ++i) {
        int n = ty + i * 8;
        Wt[(size_t)(n0 + n) * K + k0 + tx] = f2bf(t[tx][n]);
    }
}

// ---------------------------------------------------------------------------
// bf16 MFMA GEMM: C[M,N] = act( A[M,K] @ Wt[N,K]^T + bias [+ res] )
// BM=128, BN=64, BK=32; 256 threads = 4 waves; wave tile 32x64.
template<bool OUT_BF, bool GELU_ACT, bool RES>
__global__ __launch_bounds__(256) void gemm_bf(
    const ushort_t* __restrict__ A, const ushort_t* __restrict__ Bt,
    const float* __restrict__ bias, const float* __restrict__ res,
    void* __restrict__ C, int M, int N, int K)
{
    __shared__ __align__(16) ushort_t As[128][40];
    __shared__ __align__(16) ushort_t Bs[64][40];
    int tid = threadIdx.x;
    int wid = tid >> 6, lane = tid & 63;
    int h = lane >> 4, c = lane & 15;
    int bx = blockIdx.x, by = blockIdx.y;

    f32x4 acc[2][4] = {};

    int arow = tid >> 2, ac = tid & 3;   // staging row 0..63, 16B chunk 0..3
    const ushort_t* Ap = A  + (size_t)(by * 128 + arow) * K + ac * 8;
    const ushort_t* Bp = Bt + (size_t)(bx * 64  + arow) * K + ac * 8;

    for (int k0 = 0; k0 < K; k0 += 32) {
        s16x8 a0 = *(const s16x8*)(Ap + k0);
        s16x8 a1 = *(const s16x8*)(Ap + (size_t)64 * K + k0);
        s16x8 b0 = *(const s16x8*)(Bp + k0);
        __syncthreads();                 // prior mfma reads done
        *(s16x8*)&As[arow][ac * 8]      = a0;
        *(s16x8*)&As[64 + arow][ac * 8] = a1;
        *(s16x8*)&Bs[arow][ac * 8]      = b0;
        __syncthreads();                 // tiles visible

        s16x8 af[2], bf[4];
        #pragma unroll
        for (int i = 0; i < 2; ++i)
            af[i] = *(const s16x8*)&As[wid * 32 + i * 16 + c][h * 8];
        #pragma unroll
        for (int j = 0; j < 4; ++j)
            bf[j] = *(const s16x8*)&Bs[j * 16 + c][h * 8];
        #pragma unroll
        for (int i = 0; i < 2; ++i)
            #pragma unroll
            for (int j = 0; j < 4; ++j)
                acc[i][j] = mfma16x16x32(af[i], bf[j], acc[i][j]);
    }

    float bj[4];
    #pragma unroll
    for (int j = 0; j < 4; ++j) bj[j] = bias[bx * 64 + j * 16 + c];
    #pragma unroll
    for (int i = 0; i < 2; ++i) {
        #pragma unroll
        for (int r = 0; r < 4; ++r) {
            int row = by * 128 + wid * 32 + i * 16 + h * 4 + r;
            #pragma unroll
            for (int j = 0; j < 4; ++j) {
                int col = bx * 64 + j * 16 + c;
                float v = acc[i][j][r] + bj[j];
                if (RES) v += res[(size_t)row * N + col];
                if (GELU_ACT) {
                    float t = v;
                    v = 0.5f * t * (1.f + tanhf(0.7978845608028654f *
                                                (t + 0.044715f * t * t * t)));
                }
                if (OUT_BF) ((ushort_t*)C)[(size_t)row * N + col] = f2bf(v);
                else        ((float*)C)[(size_t)row * N + col]    = v;
            }
        }
    }
}

// ---------------------------------------------------------------------------
// Split-K causal flash attention (partial pass). Piece = up to 11 key-tiles
// (704 keys). Per (b,h): 63 pieces -> grid 2016 blocks = ~8064 waves (vs 4096
// before): fixes the 19.6% occupancy + causal-triangle tail. Each block
// computes partial (m, l, unnormalized O) for its 64 q-rows over its key
// range; attn_merge combines <=3 pieces/row. Mask applied only on the
// diagonal tile (wave-uniform branch); psum accumulated in f32.
#define QB 64
#define KSTR 40
#define VSTR 88
#define PSTR 72
#define PTILES 11
__global__ __launch_bounds__(256) void attn_kernel(
    const ushort_t* __restrict__ qkv, ushort_t* __restrict__ o_part,
    float* __restrict__ ml_part)
{
    __shared__ __align__(16) ushort_t Ks[QB][KSTR];
    __shared__ __align__(16) ushort_t Vt[DD][VSTR];
    __shared__ __align__(16) ushort_t Ps[4][16][PSTR];

    int tid  = threadIdx.x;
    int p    = 62 - blockIdx.x;              // heavy (high qt) first
    int qt, ks;
    if (p < 11)      { qt = p;                ks = 0; }
    else if (p < 33) { qt = 11 + (p-11) / 2;  ks = (p-11) % 2; }
    else             { qt = 22 + (p-33) / 3;  ks = (p-33) % 3; }
    int hh   = blockIdx.y, b = blockIdx.z;
    int wid  = tid >> 6, lane = tid & 63;
    int h    = lane >> 4, c = lane & 15;

    const float scale = 0.17677669529663687f;  // 1/sqrt(32)

    // Q A-frag: lane holds Q[row=c][h*8+j]
    int qfrow = qt * QB + wid * 16 + c;
    s16x8 qfrag = *(const s16x8*)(qkv + ((size_t)(b * SS + qfrow)) * (3*EE)
                                  + hh * DD + h * 8);

    f32x4 o0 = {0.f,0.f,0.f,0.f}, o1 = {0.f,0.f,0.f,0.f};
    float m[4] = { -INFINITY, -INFINITY, -INFINITY, -INFINITY };
    float l[4] = { 0.f, 0.f, 0.f, 0.f };

    int srow = tid >> 2, scq = tid & 3;
    int t0 = ks * PTILES;
    int t1 = min(t0 + PTILES, qt + 1);
    for (int kt = t0; kt < t1; ++kt) {
        int k0 = kt * QB;
        const ushort_t* kb = qkv + ((size_t)(b * SS + k0)) * (3*EE) + hh * DD + EE;
        const ushort_t* vb = kb + EE;

        __syncthreads();
        {
            s16x8 kv = *(const s16x8*)(kb + (size_t)srow * (3*EE) + scq * 8);
            *(s16x8*)&Ks[srow][scq * 8] = kv;
            s16x8 vv = *(const s16x8*)(vb + (size_t)srow * (3*EE) + scq * 8);
            int d0 = scq * 8;
            #pragma unroll
            for (int j = 0; j < 8; ++j) Vt[d0 + j][srow] = (ushort_t)vv[j];
        }
        __syncthreads();

        // QK: 4 mfmas
        f32x4 sg[4];
        #pragma unroll
        for (int g = 0; g < 4; ++g) {
            s16x8 kf = *(const s16x8*)&Ks[g * 16 + c][h * 8];
            f32x4 z = {0.f,0.f,0.f,0.f};
            sg[g] = mfma16x16x32(qfrag, kf, z);
        }

        bool diag = (kt == qt);   // wave-uniform

        // softmax rows R = h*4+r
        #pragma unroll
        for (int r = 0; r < 4; ++r) {
            float sv[4];
            #pragma unroll
            for (int g = 0; g < 4; ++g) sv[g] = sg[g][r] * scale;
            if (diag) {
                int qrow = qt * QB + wid * 16 + h * 4 + r;
                #pragma unroll
                for (int g = 0; g < 4; ++g)
                    if (k0 + g * 16 + c > qrow) sv[g] = -INFINITY;
            }
            float bm = fmaxf(fmaxf(sv[0], sv[1]), fmaxf(sv[2], sv[3]));
            #pragma unroll
            for (int off = 1; off <= 8; off <<= 1) bm = fmaxf(bm, __shfl_xor(bm, off));
            float nm   = fmaxf(m[r], bm);
            float corr = __expf(m[r] - nm);   // exp(-inf)=0 on first tile
            m[r] = nm;
            float psum = 0.f;
            #pragma unroll
            for (int g = 0; g < 4; ++g) {
                float pf = __expf(sv[g] - nm);   // masked: exp(-inf)=0
                Ps[wid][h * 4 + r][g * 16 + c] = f2bf(pf);
                psum += pf;
            }
            #pragma unroll
            for (int off = 1; off <= 8; off <<= 1) psum += __shfl_xor(psum, off);
            l[r] = l[r] * corr + psum;
            o0[r] *= corr;
            o1[r] *= corr;
        }

        // PV: 2 kc x 2 dc mfmas
        #pragma unroll
        for (int kc = 0; kc < 2; ++kc) {
            s16x8 pf = *(const s16x8*)&Ps[wid][c][kc * 32 + h * 8];
            s16x8 v0 = *(const s16x8*)&Vt[c][kc * 32 + h * 8];
            s16x8 v1 = *(const s16x8*)&Vt[16 + c][kc * 32 + h * 8];
            o0 = mfma16x16x32(pf, v0, o0);
            o1 = mfma16x16x32(pf, v1, o1);
        }
    }

    // write partials (unnormalized O in bf16; m,l in f32)
    size_t rbase = (size_t)(b * HH + hh) * SS;
    #pragma unroll
    for (int r = 0; r < 4; ++r) {
        int qrow = qt * QB + wid * 16 + h * 4 + r;
        size_t rl = rbase + qrow;
        ushort_t* op = o_part + ((size_t)ks * NRL + rl) * DD;
        op[c]      = f2bf(o0[r]);
        op[16 + c] = f2bf(o1[r]);
        if (c == 0) {
            float* mp = ml_part + ((size_t)ks * NRL + rl) * 2;
            mp[0] = m[r];
            mp[1] = l[r];
        }
    }
}

// ---------------------------------------------------------------------------
// Merge <=3 split-K partials per (b,h,s) row -> attno bf16.
__global__ __launch_bounds__(256) void attn_merge(
    const ushort_t* __restrict__ o_part, const float* __restrict__ ml_part,
    ushort_t* __restrict__ attno)
{
    int g = blockIdx.x * 256 + threadIdx.x;   // 0 .. NRL*8-1
    int rl = g >> 3;
    int d0 = (g & 7) * 4;
    int srow = rl & (SS - 1);
    int qt = srow >> 6;
    int np = (qt < 11) ? 1 : (qt < 22 ? 2 : 3);

    float mv[3], lv[3];
    float M = -INFINITY;
    #pragma unroll
    for (int i = 0; i < 3; ++i) {
        if (i < np) {
            const float* mp = ml_part + ((size_t)i * NRL + rl) * 2;
            mv[i] = mp[0]; lv[i] = mp[1];
            M = fmaxf(M, mv[i]);
        }
    }
    float acc0 = 0.f, acc1 = 0.f, acc2 = 0.f, acc3 = 0.f, L = 0.f;
    #pragma unroll
    for (int i = 0; i < 3; ++i) {
        if (i < np) {
            float w = __expf(mv[i] - M);
            L += w * lv[i];
            ushort4 ov = *(const ushort4*)(o_part + ((size_t)i * NRL + rl) * DD + d0);
            acc0 += w * bf2f(ov.x); acc1 += w * bf2f(ov.y);
            acc2 += w * bf2f(ov.z); acc3 += w * bf2f(ov.w);
        }
    }
    float inv = 1.f / L;
    int b  = rl >> 14;           // /(HH*SS)
    int hh = (rl >> 11) & 7;     // /SS % HH
    ushort4 w4 = { f2bf(acc0*inv), f2bf(acc1*inv), f2bf(acc2*inv), f2bf(acc3*inv) };
    *(ushort4*)(attno + ((size_t)(b * SS + srow)) * EE + hh * DD + d0) = w4;
}

// ---------------------------------------------------------------------------
extern "C" void kernel_launch(void* const* d_in, const int* in_sizes, int n_in,
                              void* d_out, int out_size, void* d_ws, size_t ws_size,
                              hipStream_t stream)
{
    const int*   ids    = (const int*)  d_in[0];
    const float* wte    = (const float*)d_in[1];
    const float* wpe    = (const float*)d_in[2];
    const float* ln1_g  = (const float*)d_in[3];
    const float* ln1_b  = (const float*)d_in[4];
    const float* qkv_w  = (const float*)d_in[5];
    const float* qkv_b  = (const float*)d_in[6];
    const float* proj_w = (const float*)d_in[7];
    const float* proj_b = (const float*)d_in[8];
    const float* ln2_g  = (const float*)d_in[9];
    const float* ln2_b  = (const float*)d_in[10];
    const float* fc1_w  = (const float*)d_in[11];
    const float* fc1_b  = (const float*)d_in[12];
    const float* fc2_w  = (const float*)d_in[13];
    const float* fc2_b  = (const float*)d_in[14];
    const float* lnf_g  = (const float*)d_in[15];
    const float* lnf_b  = (const float*)d_in[16];

    float*    h        = (float*)d_ws;                         // 8192*256 f32
    ushort_t* x_bf     = (ushort_t*)(h + (size_t)NROWS*EE);    // 8192*256
    ushort_t* qkv_bf   = x_bf   + (size_t)NROWS*EE;            // 8192*768
    ushort_t* attno_bf = qkv_bf + (size_t)NROWS*3*EE;          // 8192*256
    ushort_t* m1_bf    = attno_bf + (size_t)NROWS*EE;          // 8192*1024
    ushort_t* wq_t     = m1_bf  + (size_t)NROWS*NI;            // [2][768][256]
    ushort_t* wp_t     = wq_t   + (size_t)2*3*EE*EE;           // [2][256][256]
    ushort_t* w1_t     = wp_t   + (size_t)2*EE*EE;             // [2][1024][256]
    ushort_t* w2_t     = w1_t   + (size_t)2*EE*NI;             // [2][256][1024]

    // split-K scratch overlays (regions dead during attention):
    ushort_t* o_part   = m1_bf;              // 3*65536*32 ushorts = 12.6MB < 16MB
    float*    ml_part  = (float*)x_bf;       // 3*65536*2  f32     = 1.6MB  < 4MB

    // one-time (per call) weight transpose+convert
    for (int l = 0; l < LL; ++l) {
        wconv_kernel<<<dim3(3*EE/32, EE/32), 256, 0, stream>>>(
            qkv_w + (size_t)l*EE*3*EE, wq_t + (size_t)l*3*EE*EE, EE, 3*EE);
        wconv_kernel<<<dim3(EE/32, EE/32), 256, 0, stream>>>(
            proj_w + (size_t)l*EE*EE, wp_t + (size_t)l*EE*EE, EE, EE);
        wconv_kernel<<<dim3(NI/32, EE/32), 256, 0, stream>>>(
            fc1_w + (size_t)l*EE*NI, w1_t + (size_t)l*EE*NI, EE, NI);
        wconv_kernel<<<dim3(EE/32, NI/32), 256, 0, stream>>>(
            fc2_w + (size_t)l*NI*EE, w2_t + (size_t)l*NI*EE, NI, EE);
    }

    embed_kernel<<<NROWS/4, 256, 0, stream>>>(ids, wte, wpe, h);

    for (int l = 0; l < LL; ++l) {
        ln_kernel<true><<<NROWS/4, 256, 0, stream>>>(h, ln1_g + l*EE, ln1_b + l*EE, x_bf);
        gemm_bf<true,false,false><<<dim3(3*EE/64, NROWS/128), 256, 0, stream>>>(
            x_bf, wq_t + (size_t)l*3*EE*EE, qkv_b + (size_t)l*3*EE, nullptr,
            qkv_bf, NROWS, 3*EE, EE);
        attn_kernel<<<dim3(63, HH, BB), 256, 0, stream>>>(qkv_bf, o_part, ml_part);
        attn_merge<<<NRL*8/256, 256, 0, stream>>>(o_part, ml_part, attno_bf);
        gemm_bf<false,false,true><<<dim3(EE/64, NROWS/128), 256, 0, stream>>>(
            attno_bf, wp_t + (size_t)l*EE*EE, proj_b + (size_t)l*EE, h,
            h, NROWS, EE, EE);
        ln_kernel<true><<<NROWS/4, 256, 0, stream>>>(h, ln2_g + l*EE, ln2_b + l*EE, x_bf);
        gemm_bf<true,true,false><<<dim3(NI/64, NROWS/128), 256, 0, stream>>>(
            x_bf, w1_t + (size_t)l*EE*NI, fc1_b + (size_t)l*NI, nullptr,
            m1_bf, NROWS, NI, EE);
        gemm_bf<false,false,true><<<dim3(EE/64, NROWS/128), 256, 0, stream>>>(
            m1_bf, w2_t + (size_t)l*NI*EE, fc2_b + (size_t)l*EE, h,
            h, NROWS, EE, NI);
    }

    ln_kernel<false><<<NROWS/4, 256, 0, stream>>>(h, lnf_g, lnf_b, (float*)d_out);
}

// Round 10
// 294.557 us; speedup vs baseline: 48.3934x; 1.0425x over previous
//
#include <hip/hip_runtime.h>
#include <hip/hip_bf16.h>
#include <math.h>

// Problem dims (fixed by reference)
#define BB 4
#define SS 2048
#define EE 256
#define HH 8
#define DD 32
#define LL 2
#define NI 1024
#define NROWS (BB*SS)   // 8192
#define NRL   (BB*HH*SS) // 65536 flat (b,h,s) rows

typedef float f32x4 __attribute__((ext_vector_type(4)));
typedef short s16x8 __attribute__((ext_vector_type(8)));
typedef __bf16 bf16x8 __attribute__((ext_vector_type(8)));
typedef unsigned short ushort_t;

__device__ __forceinline__ unsigned short f2bf(float f) {
    unsigned u = __float_as_uint(f);
    u += 0x7fff + ((u >> 16) & 1);          // round-to-nearest-even
    return (unsigned short)(u >> 16);
}
__device__ __forceinline__ float bf2f(unsigned short s) {
    return __uint_as_float((unsigned)s << 16);
}
__device__ __forceinline__ f32x4 mfma16x16x32(s16x8 a, s16x8 b, f32x4 c) {
    return __builtin_amdgcn_mfma_f32_16x16x32_bf16(
        __builtin_bit_cast(bf16x8, a), __builtin_bit_cast(bf16x8, b), c, 0, 0, 0);
}

// ---------------------------------------------------------------------------
// Embedding, 4 rows per 256-thread block (wave per row).
__global__ __launch_bounds__(256) void embed_kernel(
    const int* __restrict__ ids, const float* __restrict__ wte,
    const float* __restrict__ wpe, float* __restrict__ h)
{
    int row  = blockIdx.x * 4 + (threadIdx.x >> 6);
    int s    = row & (SS - 1);
    int lane = threadIdx.x & 63;
    int id   = ids[row];
    float4 a = *(const float4*)(wte + (size_t)id * EE + lane * 4);
    float4 p = *(const float4*)(wpe + (size_t)s  * EE + lane * 4);
    float4 o = { a.x + p.x, a.y + p.y, a.z + p.z, a.w + p.w };
    *(float4*)(h + (size_t)row * EE + lane * 4) = o;
}

// ---------------------------------------------------------------------------
// LayerNorm over E=256; 4 rows per 256-thread block (wave per row).
template<bool OUTBF>
__global__ __launch_bounds__(256) void ln_kernel(
    const float* __restrict__ in, const float* __restrict__ g,
    const float* __restrict__ b, void* __restrict__ out)
{
    int row  = blockIdx.x * 4 + (threadIdx.x >> 6);
    int lane = threadIdx.x & 63;
    float4 v = *(const float4*)(in + (size_t)row * EE + lane * 4);
    float s  = v.x + v.y + v.z + v.w;
    float ss = v.x*v.x + v.y*v.y + v.z*v.z + v.w*v.w;
    #pragma unroll
    for (int off = 32; off; off >>= 1) {
        s  += __shfl_xor(s,  off);
        ss += __shfl_xor(ss, off);
    }
    float mu  = s * (1.f / EE);
    float var = ss * (1.f / EE) - mu * mu;
    float rs  = rsqrtf(var + 1e-5f);
    float4 gv = *(const float4*)(g + lane * 4);
    float4 bv = *(const float4*)(b + lane * 4);
    float4 o;
    o.x = (v.x - mu) * rs * gv.x + bv.x;
    o.y = (v.y - mu) * rs * gv.y + bv.y;
    o.z = (v.z - mu) * rs * gv.z + bv.z;
    o.w = (v.w - mu) * rs * gv.w + bv.w;
    if (OUTBF) {
        ushort4 w = { f2bf(o.x), f2bf(o.y), f2bf(o.z), f2bf(o.w) };
        *(ushort4*)((ushort_t*)out + (size_t)row * EE + lane * 4) = w;
    } else {
        *(float4*)((float*)out + (size_t)row * EE + lane * 4) = o;
    }
}

// ---------------------------------------------------------------------------
// Weight transpose+convert: W[K,N] f32 -> Wt[N,K] bf16. Grid (N/32, K/32).
__global__ __launch_bounds__(256) void wconv_kernel(
    const float* __restrict__ W, ushort_t* __restrict__ Wt, int K, int N)
{
    __shared__ float t[32][33];
    int n0 = blockIdx.x * 32, k0 = blockIdx.y * 32;
    int tx = threadIdx.x & 31, ty = threadIdx.x >> 5;   // ty 0..7
    #pragma unroll
    for (int i = 0; i < 4; ++i) {
        int k = ty + i * 8;
        t[k][tx] = W[(size_t)(k0 + k) * N + n0 + tx];
    }
    __syncthreads();
    #pragma unroll
    for (int i = 0; i < 4; ++i) {
        int n = ty + i * 8;
        Wt[(size_t)(n0 + n) * K + k0 + tx] = f2bf(t[tx][n]);
    }
}

// ---------------------------------------------------------------------------
// bf16 MFMA GEMM: C[M,N] = act( A[M,K] @ Wt[N,K]^T + bias [+ res] )
// MI = M-frags per wave: MI=2 -> BM=128, MI=1 -> BM=64 (for skinny-N GEMMs:
// doubles grid, fixing the 1-block/CU latency starvation at N=256).
// BN=64, BK=32; 256 threads = 4 waves. QSC: pre-scale cols<EE by 1/sqrt(D)
// (folds attention's softmax scale into Q at zero cost).
template<int MI, bool OUT_BF, bool GELU_ACT, bool RES, bool QSC>
__global__ __launch_bounds__(256) void gemm_bf(
    const ushort_t* __restrict__ A, const ushort_t* __restrict__ Bt,
    const float* __restrict__ bias, const float* __restrict__ res,
    void* __restrict__ C, int M, int N, int K)
{
    __shared__ __align__(16) ushort_t As[MI*64][40];
    __shared__ __align__(16) ushort_t Bs[64][40];
    int tid = threadIdx.x;
    int wid = tid >> 6, lane = tid & 63;
    int h = lane >> 4, c = lane & 15;
    int bx = blockIdx.x, by = blockIdx.y;

    f32x4 acc[MI][4] = {};

    int arow = tid >> 2, ac = tid & 3;   // staging row 0..63, 16B chunk 0..3
    const ushort_t* Ap = A  + (size_t)(by * (MI*64) + arow) * K + ac * 8;
    const ushort_t* Bp = Bt + (size_t)(bx * 64     + arow) * K + ac * 8;

    for (int k0 = 0; k0 < K; k0 += 32) {
        s16x8 av[MI];
        #pragma unroll
        for (int i = 0; i < MI; ++i)
            av[i] = *(const s16x8*)(Ap + (size_t)i * 64 * K + k0);
        s16x8 b0 = *(const s16x8*)(Bp + k0);
        __syncthreads();                 // prior mfma reads done
        #pragma unroll
        for (int i = 0; i < MI; ++i)
            *(s16x8*)&As[i * 64 + arow][ac * 8] = av[i];
        *(s16x8*)&Bs[arow][ac * 8] = b0;
        __syncthreads();                 // tiles visible

        s16x8 af[MI], bfr[4];
        #pragma unroll
        for (int i = 0; i < MI; ++i)
            af[i] = *(const s16x8*)&As[wid * (MI*16) + i * 16 + c][h * 8];
        #pragma unroll
        for (int j = 0; j < 4; ++j)
            bfr[j] = *(const s16x8*)&Bs[j * 16 + c][h * 8];
        #pragma unroll
        for (int i = 0; i < MI; ++i)
            #pragma unroll
            for (int j = 0; j < 4; ++j)
                acc[i][j] = mfma16x16x32(af[i], bfr[j], acc[i][j]);
    }

    float bj[4];
    #pragma unroll
    for (int j = 0; j < 4; ++j) bj[j] = bias[bx * 64 + j * 16 + c];
    #pragma unroll
    for (int i = 0; i < MI; ++i) {
        #pragma unroll
        for (int r = 0; r < 4; ++r) {
            int row = by * (MI*64) + wid * (MI*16) + i * 16 + h * 4 + r;
            #pragma unroll
            for (int j = 0; j < 4; ++j) {
                int col = bx * 64 + j * 16 + c;
                float v = acc[i][j][r] + bj[j];
                if (QSC && col < EE) v *= 0.17677669529663687f;  // 1/sqrt(32)
                if (RES) v += res[(size_t)row * N + col];
                if (GELU_ACT) {
                    float t = v;
                    v = 0.5f * t * (1.f + tanhf(0.7978845608028654f *
                                                (t + 0.044715f * t * t * t)));
                }
                if (OUT_BF) ((ushort_t*)C)[(size_t)row * N + col] = f2bf(v);
                else        ((float*)C)[(size_t)row * N + col]    = v;
            }
        }
    }
}

// ---------------------------------------------------------------------------
// Split-K causal flash attention (partial pass). PTILES=8 -> 80 pieces/(b,h)
// = 2560 blocks = 10240 waves > 8192 slots: scheduler BACKFILLS as pieces
// finish (round-8 fix: 2016 blocks were all-resident -> no backfill, makespan
// set by 11-tile pieces; avg/max = 37% occupancy). Max piece 8 tiles; <=4
// partials/row; partial slots exactly fill the dead m1 region.
// Vt columns XOR-swizzled (col = key ^ ((dim>>3)<<4)) -> transpose-staging
// writes hit all 32 banks (was 4-way: 8-row stride = 1408B = 0 mod 128).
// Q pre-scaled in the QKV GEMM (QSC) -> no scale mult here.
#define QB 64
#define KSTR 40
#define VSTR 88
#define PSTR 72
#define PTILES 8
__global__ __launch_bounds__(256) void attn_kernel(
    const ushort_t* __restrict__ qkv, ushort_t* __restrict__ o_part,
    float* __restrict__ ml_part)
{
    __shared__ __align__(16) ushort_t Ks[QB][KSTR];
    __shared__ __align__(16) ushort_t Vt[DD][VSTR];
    __shared__ __align__(16) ushort_t Ps[4][16][PSTR];

    int tid  = threadIdx.x;
    int p    = 79 - blockIdx.x;              // heavy (high qt) first
    int qt, ks;
    if (p < 8)       { qt = p;                 ks = 0; }
    else if (p < 24) { qt = 8  + ((p-8)  >> 1); ks = (p-8)  & 1; }
    else if (p < 48) { qt = 16 + (p-24) / 3;    ks = (p-24) % 3; }
    else             { qt = 24 + ((p-48) >> 2); ks = (p-48) & 3; }
    int hh   = blockIdx.y, b = blockIdx.z;
    int wid  = tid >> 6, lane = tid & 63;
    int h    = lane >> 4, c = lane & 15;

    // Q A-frag: lane holds Q[row=c][h*8+j] (already scaled by 1/sqrt(D))
    int qfrow = qt * QB + wid * 16 + c;
    s16x8 qfrag = *(const s16x8*)(qkv + ((size_t)(b * SS + qfrow)) * (3*EE)
                                  + hh * DD + h * 8);

    f32x4 o0 = {0.f,0.f,0.f,0.f}, o1 = {0.f,0.f,0.f,0.f};
    float m[4] = { -INFINITY, -INFINITY, -INFINITY, -INFINITY };
    float l[4] = { 0.f, 0.f, 0.f, 0.f };

    int srow = tid >> 2, scq = tid & 3;
    int t0 = ks * PTILES;
    int t1 = min(t0 + PTILES, qt + 1);
    for (int kt = t0; kt < t1; ++kt) {
        int k0 = kt * QB;
        const ushort_t* kb = qkv + ((size_t)(b * SS + k0)) * (3*EE) + hh * DD + EE;
        const ushort_t* vb = kb + EE;

        __syncthreads();
        {
            s16x8 kv = *(const s16x8*)(kb + (size_t)srow * (3*EE) + scq * 8);
            *(s16x8*)&Ks[srow][scq * 8] = kv;
            s16x8 vv = *(const s16x8*)(vb + (size_t)srow * (3*EE) + scq * 8);
            int d0 = scq * 8;
            int colw = srow ^ (scq << 4);          // XOR swizzle (see header)
            #pragma unroll
            for (int j = 0; j < 8; ++j) Vt[d0 + j][colw] = (ushort_t)vv[j];
        }
        __syncthreads();

        // QK: 4 mfmas
        f32x4 sg[4];
        #pragma unroll
        for (int g = 0; g < 4; ++g) {
            s16x8 kf = *(const s16x8*)&Ks[g * 16 + c][h * 8];
            f32x4 z = {0.f,0.f,0.f,0.f};
            sg[g] = mfma16x16x32(qfrag, kf, z);
        }

        bool diag = (kt == qt);   // wave-uniform

        // softmax rows R = h*4+r
        #pragma unroll
        for (int r = 0; r < 4; ++r) {
            float sv[4];
            #pragma unroll
            for (int g = 0; g < 4; ++g) sv[g] = sg[g][r];
            if (diag) {
                int qrow = qt * QB + wid * 16 + h * 4 + r;
                #pragma unroll
                for (int g = 0; g < 4; ++g)
                    if (k0 + g * 16 + c > qrow) sv[g] = -INFINITY;
            }
            float bm = fmaxf(fmaxf(sv[0], sv[1]), fmaxf(sv[2], sv[3]));
            #pragma unroll
            for (int off = 1; off <= 8; off <<= 1) bm = fmaxf(bm, __shfl_xor(bm, off));
            float nm   = fmaxf(m[r], bm);
            float corr = __expf(m[r] - nm);   // exp(-inf)=0 on first tile
            m[r] = nm;
            float psum = 0.f;
            #pragma unroll
            for (int g = 0; g < 4; ++g) {
                float pf = __expf(sv[g] - nm);   // masked: exp(-inf)=0
                Ps[wid][h * 4 + r][g * 16 + c] = f2bf(pf);
                psum += pf;
            }
            #pragma unroll
            for (int off = 1; off <= 8; off <<= 1) psum += __shfl_xor(psum, off);
            l[r] = l[r] * corr + psum;
            o0[r] *= corr;
            o1[r] *= corr;
        }

        // PV: 2 kc x 2 dc mfmas (Vt reads follow the XOR swizzle)
        #pragma unroll
        for (int kc = 0; kc < 2; ++kc) {
            int kbase = kc * 32 + h * 8;
            s16x8 pf = *(const s16x8*)&Ps[wid][c][kbase];
            s16x8 v0 = *(const s16x8*)&Vt[c]     [kbase ^ ((c >> 3) << 4)];
            s16x8 v1 = *(const s16x8*)&Vt[16 + c][kbase ^ (((16 + c) >> 3) << 4)];
            o0 = mfma16x16x32(pf, v0, o0);
            o1 = mfma16x16x32(pf, v1, o1);
        }
    }

    // write partials (unnormalized O in bf16; m,l in f32)
    size_t rbase = (size_t)(b * HH + hh) * SS;
    #pragma unroll
    for (int r = 0; r < 4; ++r) {
        int qrow = qt * QB + wid * 16 + h * 4 + r;
        size_t rl = rbase + qrow;
        ushort_t* op = o_part + ((size_t)ks * NRL + rl) * DD;
        op[c]      = f2bf(o0[r]);
        op[16 + c] = f2bf(o1[r]);
        if (c == 0) {
            float* mp = ml_part + ((size_t)ks * NRL + rl) * 2;
            mp[0] = m[r];
            mp[1] = l[r];
        }
    }
}

// ---------------------------------------------------------------------------
// Merge <=4 split-K partials per (b,h,s) row -> attno bf16.
__global__ __launch_bounds__(256) void attn_merge(
    const ushort_t* __restrict__ o_part, const float* __restrict__ ml_part,
    ushort_t* __restrict__ attno)
{
    int g = blockIdx.x * 256 + threadIdx.x;   // 0 .. NRL*8-1
    int rl = g >> 3;
    int d0 = (g & 7) * 4;
    int srow = rl & (SS - 1);
    int qt = srow >> 6;
    int np = (qt >> 3) + 1;                   // ceil((qt+1)/PTILES)

    float mv[4], lv[4];
    float M = -INFINITY;
    #pragma unroll
    for (int i = 0; i < 4; ++i) {
        if (i < np) {
            const float* mp = ml_part + ((size_t)i * NRL + rl) * 2;
            mv[i] = mp[0]; lv[i] = mp[1];
            M = fmaxf(M, mv[i]);
        }
    }
    float acc0 = 0.f, acc1 = 0.f, acc2 = 0.f, acc3 = 0.f, L = 0.f;
    #pragma unroll
    for (int i = 0; i < 4; ++i) {
        if (i < np) {
            float w = __expf(mv[i] - M);
            L += w * lv[i];
            ushort4 ov = *(const ushort4*)(o_part + ((size_t)i * NRL + rl) * DD + d0);
            acc0 += w * bf2f(ov.x); acc1 += w * bf2f(ov.y);
            acc2 += w * bf2f(ov.z); acc3 += w * bf2f(ov.w);
        }
    }
    float inv = 1.f / L;
    int b  = rl >> 14;           // /(HH*SS)
    int hh = (rl >> 11) & 7;     // /SS % HH
    ushort4 w4 = { f2bf(acc0*inv), f2bf(acc1*inv), f2bf(acc2*inv), f2bf(acc3*inv) };
    *(ushort4*)(attno + ((size_t)(b * SS + srow)) * EE + hh * DD + d0) = w4;
}

// ---------------------------------------------------------------------------
extern "C" void kernel_launch(void* const* d_in, const int* in_sizes, int n_in,
                              void* d_out, int out_size, void* d_ws, size_t ws_size,
                              hipStream_t stream)
{
    const int*   ids    = (const int*)  d_in[0];
    const float* wte    = (const float*)d_in[1];
    const float* wpe    = (const float*)d_in[2];
    const float* ln1_g  = (const float*)d_in[3];
    const float* ln1_b  = (const float*)d_in[4];
    const float* qkv_w  = (const float*)d_in[5];
    const float* qkv_b  = (const float*)d_in[6];
    const float* proj_w = (const float*)d_in[7];
    const float* proj_b = (const float*)d_in[8];
    const float* ln2_g  = (const float*)d_in[9];
    const float* ln2_b  = (const float*)d_in[10];
    const float* fc1_w  = (const float*)d_in[11];
    const float* fc1_b  = (const float*)d_in[12];
    const float* fc2_w  = (const float*)d_in[13];
    const float* fc2_b  = (const float*)d_in[14];
    const float* lnf_g  = (const float*)d_in[15];
    const float* lnf_b  = (const float*)d_in[16];

    float*    h        = (float*)d_ws;                         // 8192*256 f32
    ushort_t* x_bf     = (ushort_t*)(h + (size_t)NROWS*EE);    // 8192*256
    ushort_t* qkv_bf   = x_bf   + (size_t)NROWS*EE;            // 8192*768
    ushort_t* attno_bf = qkv_bf + (size_t)NROWS*3*EE;          // 8192*256
    ushort_t* m1_bf    = attno_bf + (size_t)NROWS*EE;          // 8192*1024
    ushort_t* wq_t     = m1_bf  + (size_t)NROWS*NI;            // [2][768][256]
    ushort_t* wp_t     = wq_t   + (size_t)2*3*EE*EE;           // [2][256][256]
    ushort_t* w1_t     = wp_t   + (size_t)2*EE*EE;             // [2][1024][256]
    ushort_t* w2_t     = w1_t   + (size_t)2*EE*NI;             // [2][256][1024]

    // split-K scratch overlays (regions dead during attention):
    ushort_t* o_part   = m1_bf;              // 4*65536*32*2B = 16.78MB == m1 region
    float*    ml_part  = (float*)x_bf;       // 4*65536*2*4B  = 2.1MB   <  x region

    // one-time (per call) weight transpose+convert
    for (int l = 0; l < LL; ++l) {
        wconv_kernel<<<dim3(3*EE/32, EE/32), 256, 0, stream>>>(
            qkv_w + (size_t)l*EE*3*EE, wq_t + (size_t)l*3*EE*EE, EE, 3*EE);
        wconv_kernel<<<dim3(EE/32, EE/32), 256, 0, stream>>>(
            proj_w + (size_t)l*EE*EE, wp_t + (size_t)l*EE*EE, EE, EE);
        wconv_kernel<<<dim3(NI/32, EE/32), 256, 0, stream>>>(
            fc1_w + (size_t)l*EE*NI, w1_t + (size_t)l*EE*NI, EE, NI);
        wconv_kernel<<<dim3(EE/32, NI/32), 256, 0, stream>>>(
            fc2_w + (size_t)l*NI*EE, w2_t + (size_t)l*NI*EE, NI, EE);
    }

    embed_kernel<<<NROWS/4, 256, 0, stream>>>(ids, wte, wpe, h);

    for (int l = 0; l < LL; ++l) {
        ln_kernel<true><<<NROWS/4, 256, 0, stream>>>(h, ln1_g + l*EE, ln1_b + l*EE, x_bf);
        gemm_bf<2,true,false,false,true><<<dim3(3*EE/64, NROWS/128), 256, 0, stream>>>(
            x_bf, wq_t + (size_t)l*3*EE*EE, qkv_b + (size_t)l*3*EE, nullptr,
            qkv_bf, NROWS, 3*EE, EE);
        attn_kernel<<<dim3(80, HH, BB), 256, 0, stream>>>(qkv_bf, o_part, ml_part);
        attn_merge<<<NRL*8/256, 256, 0, stream>>>(o_part, ml_part, attno_bf);
        gemm_bf<1,false,false,true,false><<<dim3(EE/64, NROWS/64), 256, 0, stream>>>(
            attno_bf, wp_t + (size_t)l*EE*EE, proj_b + (size_t)l*EE, h,
            h, NROWS, EE, EE);
        ln_kernel<true><<<NROWS/4, 256, 0, stream>>>(h, ln2_g + l*EE, ln2_b + l*EE, x_bf);
        gemm_bf<2,true,true,false,false><<<dim3(NI/64, NROWS/128), 256, 0, stream>>>(
            x_bf, w1_t + (size_t)l*EE*NI, fc1_b + (size_t)l*NI, nullptr,
            m1_bf, NROWS, NI, EE);
        gemm_bf<1,false,false,true,false><<<dim3(EE/64, NROWS/64), 256, 0, stream>>>(
            m1_bf, w2_t + (size_t)l*NI*EE, fc2_b + (size_t)l*EE, h,
            h, NROWS, EE, NI);
    }

    ln_kernel<false><<<NROWS/4, 256, 0, stream>>>(h, lnf_g, lnf_b, (float*)d_out);
}

// Round 11
// 291.470 us; speedup vs baseline: 48.9059x; 1.0106x over previous
//
#include <hip/hip_runtime.h>
#include <hip/hip_bf16.h>
#include <math.h>

// Problem dims (fixed by reference)
#define BB 4
#define SS 2048
#define EE 256
#define HH 8
#define DD 32
#define LL 2
#define NI 1024
#define NROWS (BB*SS)   // 8192
#define NRL   (BB*HH*SS) // 65536 flat (b,h,s) rows

typedef float f32x4 __attribute__((ext_vector_type(4)));
typedef short s16x8 __attribute__((ext_vector_type(8)));
typedef __bf16 bf16x8 __attribute__((ext_vector_type(8)));
typedef unsigned short ushort_t;

__device__ __forceinline__ unsigned short f2bf(float f) {
    unsigned u = __float_as_uint(f);
    u += 0x7fff + ((u >> 16) & 1);          // round-to-nearest-even
    return (unsigned short)(u >> 16);
}
__device__ __forceinline__ float bf2f(unsigned short s) {
    return __uint_as_float((unsigned)s << 16);
}
__device__ __forceinline__ f32x4 mfma16x16x32(s16x8 a, s16x8 b, f32x4 c) {
    return __builtin_amdgcn_mfma_f32_16x16x32_bf16(
        __builtin_bit_cast(bf16x8, a), __builtin_bit_cast(bf16x8, b), c, 0, 0, 0);
}

// ---------------------------------------------------------------------------
// Embedding, 4 rows per 256-thread block (wave per row).
__global__ __launch_bounds__(256) void embed_kernel(
    const int* __restrict__ ids, const float* __restrict__ wte,
    const float* __restrict__ wpe, float* __restrict__ h)
{
    int row  = blockIdx.x * 4 + (threadIdx.x >> 6);
    int s    = row & (SS - 1);
    int lane = threadIdx.x & 63;
    int id   = ids[row];
    float4 a = *(const float4*)(wte + (size_t)id * EE + lane * 4);
    float4 p = *(const float4*)(wpe + (size_t)s  * EE + lane * 4);
    float4 o = { a.x + p.x, a.y + p.y, a.z + p.z, a.w + p.w };
    *(float4*)(h + (size_t)row * EE + lane * 4) = o;
}

// ---------------------------------------------------------------------------
// LayerNorm over E=256; 4 rows per 256-thread block (wave per row).
template<bool OUTBF>
__global__ __launch_bounds__(256) void ln_kernel(
    const float* __restrict__ in, const float* __restrict__ g,
    const float* __restrict__ b, void* __restrict__ out)
{
    int row  = blockIdx.x * 4 + (threadIdx.x >> 6);
    int lane = threadIdx.x & 63;
    float4 v = *(const float4*)(in + (size_t)row * EE + lane * 4);
    float s  = v.x + v.y + v.z + v.w;
    float ss = v.x*v.x + v.y*v.y + v.z*v.z + v.w*v.w;
    #pragma unroll
    for (int off = 32; off; off >>= 1) {
        s  += __shfl_xor(s,  off);
        ss += __shfl_xor(ss, off);
    }
    float mu  = s * (1.f / EE);
    float var = ss * (1.f / EE) - mu * mu;
    float rs  = rsqrtf(var + 1e-5f);
    float4 gv = *(const float4*)(g + lane * 4);
    float4 bv = *(const float4*)(b + lane * 4);
    float4 o;
    o.x = (v.x - mu) * rs * gv.x + bv.x;
    o.y = (v.y - mu) * rs * gv.y + bv.y;
    o.z = (v.z - mu) * rs * gv.z + bv.z;
    o.w = (v.w - mu) * rs * gv.w + bv.w;
    if (OUTBF) {
        ushort4 w = { f2bf(o.x), f2bf(o.y), f2bf(o.z), f2bf(o.w) };
        *(ushort4*)((ushort_t*)out + (size_t)row * EE + lane * 4) = w;
    } else {
        *(float4*)((float*)out + (size_t)row * EE + lane * 4) = o;
    }
}

// ---------------------------------------------------------------------------
// Weight transpose+convert: W[K,N] f32 -> Wt[N,K] bf16. Grid (N/32, K/32).
__global__ __launch_bounds__(256) void wconv_kernel(
    const float* __restrict__ W, ushort_t* __restrict__ Wt, int K, int N)
{
    __shared__ float t[32][33];
    int n0 = blockIdx.x * 32, k0 = blockIdx.y * 32;
    int tx = threadIdx.x & 31, ty = threadIdx.x >> 5;   // ty 0..7
    #pragma unroll
    for (int i = 0; i < 4; ++i) {
        int k = ty + i * 8;
        t[k][tx] = W[(size_t)(k0 + k) * N + n0 + tx];
    }
    __syncthreads();
    #pragma unroll
    for (int i = 0; i < 4; ++i) {
        int n = ty + i * 8;
        Wt[(size_t)(n0 + n) * K + k0 + tx] = f2bf(t[tx][n]);
    }
}

// ---------------------------------------------------------------------------
// bf16 MFMA GEMM: C[M,N] = act( A[M,K] @ Wt[N,K]^T + bias [+ res] )
// MI = M-frags per wave: MI=2 -> BM=128, MI=1 -> BM=64 (for skinny-N GEMMs).
// BN=64, BK=32; 256 threads = 4 waves. QSC: pre-scale cols<EE by 1/sqrt(D).
template<int MI, bool OUT_BF, bool GELU_ACT, bool RES, bool QSC>
__global__ __launch_bounds__(256) void gemm_bf(
    const ushort_t* __restrict__ A, const ushort_t* __restrict__ Bt,
    const float* __restrict__ bias, const float* __restrict__ res,
    void* __restrict__ C, int M, int N, int K)
{
    __shared__ __align__(16) ushort_t As[MI*64][40];
    __shared__ __align__(16) ushort_t Bs[64][40];
    int tid = threadIdx.x;
    int wid = tid >> 6, lane = tid & 63;
    int h = lane >> 4, c = lane & 15;
    int bx = blockIdx.x, by = blockIdx.y;

    f32x4 acc[MI][4] = {};

    int arow = tid >> 2, ac = tid & 3;   // staging row 0..63, 16B chunk 0..3
    const ushort_t* Ap = A  + (size_t)(by * (MI*64) + arow) * K + ac * 8;
    const ushort_t* Bp = Bt + (size_t)(bx * 64     + arow) * K + ac * 8;

    for (int k0 = 0; k0 < K; k0 += 32) {
        s16x8 av[MI];
        #pragma unroll
        for (int i = 0; i < MI; ++i)
            av[i] = *(const s16x8*)(Ap + (size_t)i * 64 * K + k0);
        s16x8 b0 = *(const s16x8*)(Bp + k0);
        __syncthreads();                 // prior mfma reads done
        #pragma unroll
        for (int i = 0; i < MI; ++i)
            *(s16x8*)&As[i * 64 + arow][ac * 8] = av[i];
        *(s16x8*)&Bs[arow][ac * 8] = b0;
        __syncthreads();                 // tiles visible

        s16x8 af[MI], bfr[4];
        #pragma unroll
        for (int i = 0; i < MI; ++i)
            af[i] = *(const s16x8*)&As[wid * (MI*16) + i * 16 + c][h * 8];
        #pragma unroll
        for (int j = 0; j < 4; ++j)
            bfr[j] = *(const s16x8*)&Bs[j * 16 + c][h * 8];
        #pragma unroll
        for (int i = 0; i < MI; ++i)
            #pragma unroll
            for (int j = 0; j < 4; ++j)
                acc[i][j] = mfma16x16x32(af[i], bfr[j], acc[i][j]);
    }

    float bj[4];
    #pragma unroll
    for (int j = 0; j < 4; ++j) bj[j] = bias[bx * 64 + j * 16 + c];
    #pragma unroll
    for (int i = 0; i < MI; ++i) {
        #pragma unroll
        for (int r = 0; r < 4; ++r) {
            int row = by * (MI*64) + wid * (MI*16) + i * 16 + h * 4 + r;
            #pragma unroll
            for (int j = 0; j < 4; ++j) {
                int col = bx * 64 + j * 16 + c;
                float v = acc[i][j][r] + bj[j];
                if (QSC && col < EE) v *= 0.17677669529663687f;  // 1/sqrt(32)
                if (RES) v += res[(size_t)row * N + col];
                if (GELU_ACT) {
                    float t = v;
                    v = 0.5f * t * (1.f + tanhf(0.7978845608028654f *
                                                (t + 0.044715f * t * t * t)));
                }
                if (OUT_BF) ((ushort_t*)C)[(size_t)row * N + col] = f2bf(v);
                else        ((float*)C)[(size_t)row * N + col]    = v;
            }
        }
    }
}

// ---------------------------------------------------------------------------
// Split-K causal flash attention (partial pass). PTILES=8, 80 pieces/(b,h).
// ROUND-11 CHANGE (T14 async-stage + T5 setprio): K/V for tile kt+1 are
// prefetched into REGISTERS during tile kt's compute. The pre-compute barrier
// waits only lgkmcnt(0) (DS writes visible) via inline asm + raw s_barrier,
// leaving the 2 prefetch global loads in flight under the MFMA/softmax phase
// (~400cy covers the ~200-400cy L2 latency). __syncthreads() would drain
// vmcnt(0) and kill the overlap; the first barrier keeps full __syncthreads()
// (its drain is free: prefetched regs are consumed immediately after).
#define QB 64
#define KSTR 40
#define VSTR 88
#define PSTR 72
#define PTILES 8
__global__ __launch_bounds__(256) void attn_kernel(
    const ushort_t* __restrict__ qkv, ushort_t* __restrict__ o_part,
    float* __restrict__ ml_part)
{
    __shared__ __align__(16) ushort_t Ks[QB][KSTR];
    __shared__ __align__(16) ushort_t Vt[DD][VSTR];
    __shared__ __align__(16) ushort_t Ps[4][16][PSTR];

    int tid  = threadIdx.x;
    int p    = 79 - blockIdx.x;              // heavy (high qt) first
    int qt, ks;
    if (p < 8)       { qt = p;                 ks = 0; }
    else if (p < 24) { qt = 8  + ((p-8)  >> 1); ks = (p-8)  & 1; }
    else if (p < 48) { qt = 16 + (p-24) / 3;    ks = (p-24) % 3; }
    else             { qt = 24 + ((p-48) >> 2); ks = (p-48) & 3; }
    int hh   = blockIdx.y, b = blockIdx.z;
    int wid  = tid >> 6, lane = tid & 63;
    int h    = lane >> 4, c = lane & 15;

    // Q A-frag: lane holds Q[row=c][h*8+j] (already scaled by 1/sqrt(D))
    int qfrow = qt * QB + wid * 16 + c;
    s16x8 qfrag = *(const s16x8*)(qkv + ((size_t)(b * SS + qfrow)) * (3*EE)
                                  + hh * DD + h * 8);

    f32x4 o0 = {0.f,0.f,0.f,0.f}, o1 = {0.f,0.f,0.f,0.f};
    float m[4] = { -INFINITY, -INFINITY, -INFINITY, -INFINITY };
    float l[4] = { 0.f, 0.f, 0.f, 0.f };

    int srow = tid >> 2, scq = tid & 3;
    int t0 = ks * PTILES;
    int t1 = min(t0 + PTILES, qt + 1);

    // prologue: load first tile's K/V rows into registers
    s16x8 kreg, vreg;
    {
        const ushort_t* kb = qkv + ((size_t)(b * SS + t0 * QB)) * (3*EE) + hh * DD + EE;
        kreg = *(const s16x8*)(kb + (size_t)srow * (3*EE) + scq * 8);
        vreg = *(const s16x8*)(kb + EE + (size_t)srow * (3*EE) + scq * 8);
    }

    for (int kt = t0; kt < t1; ++kt) {
        int k0 = kt * QB;

        __syncthreads();   // prev tile's LDS reads done (full drain is free here)

        // stage K/V from regs
        *(s16x8*)&Ks[srow][scq * 8] = kreg;
        {
            int d0 = scq * 8;
            int colw = srow ^ (scq << 4);          // XOR swizzle
            #pragma unroll
            for (int j = 0; j < 8; ++j) Vt[d0 + j][colw] = (ushort_t)vreg[j];
        }
        // issue prefetch for next tile (stays in flight across the barrier)
        if (kt + 1 < t1) {
            const ushort_t* kb2 = qkv + ((size_t)(b * SS + (kt+1) * QB)) * (3*EE)
                                  + hh * DD + EE;
            kreg = *(const s16x8*)(kb2 + (size_t)srow * (3*EE) + scq * 8);
            vreg = *(const s16x8*)(kb2 + EE + (size_t)srow * (3*EE) + scq * 8);
        }

        // barrier that waits DS only (NOT vmcnt): prefetch overlaps compute
        asm volatile("s_waitcnt lgkmcnt(0)" ::: "memory");
        __builtin_amdgcn_s_barrier();
        asm volatile("" ::: "memory");

        __builtin_amdgcn_s_setprio(1);

        // QK: 4 mfmas
        f32x4 sg[4];
        #pragma unroll
        for (int g = 0; g < 4; ++g) {
            s16x8 kf = *(const s16x8*)&Ks[g * 16 + c][h * 8];
            f32x4 z = {0.f,0.f,0.f,0.f};
            sg[g] = mfma16x16x32(qfrag, kf, z);
        }

        bool diag = (kt == qt);   // wave-uniform

        // softmax rows R = h*4+r
        #pragma unroll
        for (int r = 0; r < 4; ++r) {
            float sv[4];
            #pragma unroll
            for (int g = 0; g < 4; ++g) sv[g] = sg[g][r];
            if (diag) {
                int qrow = qt * QB + wid * 16 + h * 4 + r;
                #pragma unroll
                for (int g = 0; g < 4; ++g)
                    if (k0 + g * 16 + c > qrow) sv[g] = -INFINITY;
            }
            float bm = fmaxf(fmaxf(sv[0], sv[1]), fmaxf(sv[2], sv[3]));
            #pragma unroll
            for (int off = 1; off <= 8; off <<= 1) bm = fmaxf(bm, __shfl_xor(bm, off));
            float nm   = fmaxf(m[r], bm);
            float corr = __expf(m[r] - nm);   // exp(-inf)=0 on first tile
            m[r] = nm;
            float psum = 0.f;
            #pragma unroll
            for (int g = 0; g < 4; ++g) {
                float pf = __expf(sv[g] - nm);   // masked: exp(-inf)=0
                Ps[wid][h * 4 + r][g * 16 + c] = f2bf(pf);
                psum += pf;
            }
            #pragma unroll
            for (int off = 1; off <= 8; off <<= 1) psum += __shfl_xor(psum, off);
            l[r] = l[r] * corr + psum;
            o0[r] *= corr;
            o1[r] *= corr;
        }

        // PV: 2 kc x 2 dc mfmas (Vt reads follow the XOR swizzle)
        #pragma unroll
        for (int kc = 0; kc < 2; ++kc) {
            int kbase = kc * 32 + h * 8;
            s16x8 pf = *(const s16x8*)&Ps[wid][c][kbase];
            s16x8 v0 = *(const s16x8*)&Vt[c]     [kbase ^ ((c >> 3) << 4)];
            s16x8 v1 = *(const s16x8*)&Vt[16 + c][kbase ^ (((16 + c) >> 3) << 4)];
            o0 = mfma16x16x32(pf, v0, o0);
            o1 = mfma16x16x32(pf, v1, o1);
        }

        __builtin_amdgcn_s_setprio(0);
    }

    // write partials (unnormalized O in bf16; m,l in f32)
    size_t rbase = (size_t)(b * HH + hh) * SS;
    #pragma unroll
    for (int r = 0; r < 4; ++r) {
        int qrow = qt * QB + wid * 16 + h * 4 + r;
        size_t rl = rbase + qrow;
        ushort_t* op = o_part + ((size_t)ks * NRL + rl) * DD;
        op[c]      = f2bf(o0[r]);
        op[16 + c] = f2bf(o1[r]);
        if (c == 0) {
            float* mp = ml_part + ((size_t)ks * NRL + rl) * 2;
            mp[0] = m[r];
            mp[1] = l[r];
        }
    }
}

// ---------------------------------------------------------------------------
// Merge <=4 split-K partials per (b,h,s) row -> attno bf16.
__global__ __launch_bounds__(256) void attn_merge(
    const ushort_t* __restrict__ o_part, const float* __restrict__ ml_part,
    ushort_t* __restrict__ attno)
{
    int g = blockIdx.x * 256 + threadIdx.x;   // 0 .. NRL*8-1
    int rl = g >> 3;
    int d0 = (g & 7) * 4;
    int srow = rl & (SS - 1);
    int qt = srow >> 6;
    int np = (qt >> 3) + 1;                   // ceil((qt+1)/PTILES)

    float mv[4], lv[4];
    float M = -INFINITY;
    #pragma unroll
    for (int i = 0; i < 4; ++i) {
        if (i < np) {
            const float* mp = ml_part + ((size_t)i * NRL + rl) * 2;
            mv[i] = mp[0]; lv[i] = mp[1];
            M = fmaxf(M, mv[i]);
        }
    }
    float acc0 = 0.f, acc1 = 0.f, acc2 = 0.f, acc3 = 0.f, L = 0.f;
    #pragma unroll
    for (int i = 0; i < 4; ++i) {
        if (i < np) {
            float w = __expf(mv[i] - M);
            L += w * lv[i];
            ushort4 ov = *(const ushort4*)(o_part + ((size_t)i * NRL + rl) * DD + d0);
            acc0 += w * bf2f(ov.x); acc1 += w * bf2f(ov.y);
            acc2 += w * bf2f(ov.z); acc3 += w * bf2f(ov.w);
        }
    }
    float inv = 1.f / L;
    int b  = rl >> 14;           // /(HH*SS)
    int hh = (rl >> 11) & 7;     // /SS % HH
    ushort4 w4 = { f2bf(acc0*inv), f2bf(acc1*inv), f2bf(acc2*inv), f2bf(acc3*inv) };
    *(ushort4*)(attno + ((size_t)(b * SS + srow)) * EE + hh * DD + d0) = w4;
}

// ---------------------------------------------------------------------------
extern "C" void kernel_launch(void* const* d_in, const int* in_sizes, int n_in,
                              void* d_out, int out_size, void* d_ws, size_t ws_size,
                              hipStream_t stream)
{
    const int*   ids    = (const int*)  d_in[0];
    const float* wte    = (const float*)d_in[1];
    const float* wpe    = (const float*)d_in[2];
    const float* ln1_g  = (const float*)d_in[3];
    const float* ln1_b  = (const float*)d_in[4];
    const float* qkv_w  = (const float*)d_in[5];
    const float* qkv_b  = (const float*)d_in[6];
    const float* proj_w = (const float*)d_in[7];
    const float* proj_b = (const float*)d_in[8];
    const float* ln2_g  = (const float*)d_in[9];
    const float* ln2_b  = (const float*)d_in[10];
    const float* fc1_w  = (const float*)d_in[11];
    const float* fc1_b  = (const float*)d_in[12];
    const float* fc2_w  = (const float*)d_in[13];
    const float* fc2_b  = (const float*)d_in[14];
    const float* lnf_g  = (const float*)d_in[15];
    const float* lnf_b  = (const float*)d_in[16];

    float*    h        = (float*)d_ws;                         // 8192*256 f32
    ushort_t* x_bf     = (ushort_t*)(h + (size_t)NROWS*EE);    // 8192*256
    ushort_t* qkv_bf   = x_bf   + (size_t)NROWS*EE;            // 8192*768
    ushort_t* attno_bf = qkv_bf + (size_t)NROWS*3*EE;          // 8192*256
    ushort_t* m1_bf    = attno_bf + (size_t)NROWS*EE;          // 8192*1024
    ushort_t* wq_t     = m1_bf  + (size_t)NROWS*NI;            // [2][768][256]
    ushort_t* wp_t     = wq_t   + (size_t)2*3*EE*EE;           // [2][256][256]
    ushort_t* w1_t     = wp_t   + (size_t)2*EE*EE;             // [2][1024][256]
    ushort_t* w2_t     = w1_t   + (size_t)2*EE*NI;             // [2][256][1024]

    // split-K scratch overlays (regions dead during attention):
    ushort_t* o_part   = m1_bf;              // 4*65536*32*2B = 16.78MB == m1 region
    float*    ml_part  = (float*)x_bf;       // 4*65536*2*4B  = 2.1MB   <  x region

    // one-time (per call) weight transpose+convert
    for (int l = 0; l < LL; ++l) {
        wconv_kernel<<<dim3(3*EE/32, EE/32), 256, 0, stream>>>(
            qkv_w + (size_t)l*EE*3*EE, wq_t + (size_t)l*3*EE*EE, EE, 3*EE);
        wconv_kernel<<<dim3(EE/32, EE/32), 256, 0, stream>>>(
            proj_w + (size_t)l*EE*EE, wp_t + (size_t)l*EE*EE, EE, EE);
        wconv_kernel<<<dim3(NI/32, EE/32), 256, 0, stream>>>(
            fc1_w + (size_t)l*EE*NI, w1_t + (size_t)l*EE*NI, EE, NI);
        wconv_kernel<<<dim3(EE/32, NI/32), 256, 0, stream>>>(
            fc2_w + (size_t)l*NI*EE, w2_t + (size_t)l*NI*EE, NI, EE);
    }

    embed_kernel<<<NROWS/4, 256, 0, stream>>>(ids, wte, wpe, h);

    for (int l = 0; l < LL; ++l) {
        ln_kernel<true><<<NROWS/4, 256, 0, stream>>>(h, ln1_g + l*EE, ln1_b + l*EE, x_bf);
        gemm_bf<2,true,false,false,true><<<dim3(3*EE/64, NROWS/128), 256, 0, stream>>>(
            x_bf, wq_t + (size_t)l*3*EE*EE, qkv_b + (size_t)l*3*EE, nullptr,
            qkv_bf, NROWS, 3*EE, EE);
        attn_kernel<<<dim3(80, HH, BB), 256, 0, stream>>>(qkv_bf, o_part, ml_part);
        attn_merge<<<NRL*8/256, 256, 0, stream>>>(o_part, ml_part, attno_bf);
        gemm_bf<1,false,false,true,false><<<dim3(EE/64, NROWS/64), 256, 0, stream>>>(
            attno_bf, wp_t + (size_t)l*EE*EE, proj_b + (size_t)l*EE, h,
            h, NROWS, EE, EE);
        ln_kernel<true><<<NROWS/4, 256, 0, stream>>>(h, ln2_g + l*EE, ln2_b + l*EE, x_bf);
        gemm_bf<2,true,true,false,false><<<dim3(NI/64, NROWS/128), 256, 0, stream>>>(
            x_bf, w1_t + (size_t)l*EE*NI, fc1_b + (size_t)l*NI, nullptr,
            m1_bf, NROWS, NI, EE);
        gemm_bf<1,false,false,true,false><<<dim3(EE/64, NROWS/64), 256, 0, stream>>>(
            m1_bf, w2_t + (size_t)l*NI*EE, fc2_b + (size_t)l*EE, h,
            h, NROWS, EE, NI);
    }

    ln_kernel<false><<<NROWS/4, 256, 0, stream>>>(h, lnf_g, lnf_b, (float*)d_out);
}

// Round 12
// 272.882 us; speedup vs baseline: 52.2373x; 1.0681x over previous
//
#include <hip/hip_runtime.h>
#include <hip/hip_bf16.h>
#include <math.h>

// Problem dims (fixed by reference)
#define BB 4
#define SS 2048
#define EE 256
#define HH 8
#define DD 32
#define LL 2
#define NI 1024
#define NROWS (BB*SS)   // 8192
#define NRL   (BB*HH*SS) // 65536 flat (b,h,s) rows

typedef float f32x4 __attribute__((ext_vector_type(4)));
typedef short s16x8 __attribute__((ext_vector_type(8)));
typedef __bf16 bf16x8 __attribute__((ext_vector_type(8)));
typedef unsigned short ushort_t;

// 1/sqrt(32) * log2(e): QK scores land in log2 domain -> exp2f everywhere.
#define QSCALE 0.2550352699458294f

__device__ __forceinline__ unsigned short f2bf(float f) {
    unsigned u = __float_as_uint(f);
    u += 0x7fff + ((u >> 16) & 1);          // round-to-nearest-even
    return (unsigned short)(u >> 16);
}
__device__ __forceinline__ float bf2f(unsigned short s) {
    return __uint_as_float((unsigned)s << 16);
}
__device__ __forceinline__ f32x4 mfma16x16x32(s16x8 a, s16x8 b, f32x4 c) {
    return __builtin_amdgcn_mfma_f32_16x16x32_bf16(
        __builtin_bit_cast(bf16x8, a), __builtin_bit_cast(bf16x8, b), c, 0, 0, 0);
}

// ---------------------------------------------------------------------------
// Fused embedding + LN1(layer 0): h = wte[id]+wpe; x_bf = LN(h,g,b).
__global__ __launch_bounds__(256) void embed_ln_kernel(
    const int* __restrict__ ids, const float* __restrict__ wte,
    const float* __restrict__ wpe, const float* __restrict__ g,
    const float* __restrict__ b, float* __restrict__ h, ushort_t* __restrict__ x)
{
    int row  = blockIdx.x * 4 + (threadIdx.x >> 6);
    int s    = row & (SS - 1);
    int lane = threadIdx.x & 63;
    int id   = ids[row];
    float4 a = *(const float4*)(wte + (size_t)id * EE + lane * 4);
    float4 p = *(const float4*)(wpe + (size_t)s  * EE + lane * 4);
    float4 v = { a.x + p.x, a.y + p.y, a.z + p.z, a.w + p.w };
    *(float4*)(h + (size_t)row * EE + lane * 4) = v;
    float sm  = v.x + v.y + v.z + v.w;
    float ss2 = v.x*v.x + v.y*v.y + v.z*v.z + v.w*v.w;
    #pragma unroll
    for (int off = 32; off; off >>= 1) {
        sm  += __shfl_xor(sm,  off);
        ss2 += __shfl_xor(ss2, off);
    }
    float mu  = sm * (1.f / EE);
    float var = ss2 * (1.f / EE) - mu * mu;
    float rs  = rsqrtf(var + 1e-5f);
    float4 gv = *(const float4*)(g + lane * 4);
    float4 bv = *(const float4*)(b + lane * 4);
    ushort4 w = { f2bf((v.x - mu) * rs * gv.x + bv.x),
                  f2bf((v.y - mu) * rs * gv.y + bv.y),
                  f2bf((v.z - mu) * rs * gv.z + bv.z),
                  f2bf((v.w - mu) * rs * gv.w + bv.w) };
    *(ushort4*)(x + (size_t)row * EE + lane * 4) = w;
}

// ---------------------------------------------------------------------------
// LayerNorm over E=256; 4 rows per 256-thread block (wave per row).
template<bool OUTBF>
__global__ __launch_bounds__(256) void ln_kernel(
    const float* __restrict__ in, const float* __restrict__ g,
    const float* __restrict__ b, void* __restrict__ out)
{
    int row  = blockIdx.x * 4 + (threadIdx.x >> 6);
    int lane = threadIdx.x & 63;
    float4 v = *(const float4*)(in + (size_t)row * EE + lane * 4);
    float s  = v.x + v.y + v.z + v.w;
    float ss = v.x*v.x + v.y*v.y + v.z*v.z + v.w*v.w;
    #pragma unroll
    for (int off = 32; off; off >>= 1) {
        s  += __shfl_xor(s,  off);
        ss += __shfl_xor(ss, off);
    }
    float mu  = s * (1.f / EE);
    float var = ss * (1.f / EE) - mu * mu;
    float rs  = rsqrtf(var + 1e-5f);
    float4 gv = *(const float4*)(g + lane * 4);
    float4 bv = *(const float4*)(b + lane * 4);
    float4 o;
    o.x = (v.x - mu) * rs * gv.x + bv.x;
    o.y = (v.y - mu) * rs * gv.y + bv.y;
    o.z = (v.z - mu) * rs * gv.z + bv.z;
    o.w = (v.w - mu) * rs * gv.w + bv.w;
    if (OUTBF) {
        ushort4 w = { f2bf(o.x), f2bf(o.y), f2bf(o.z), f2bf(o.w) };
        *(ushort4*)((ushort_t*)out + (size_t)row * EE + lane * 4) = w;
    } else {
        *(float4*)((float*)out + (size_t)row * EE + lane * 4) = o;
    }
}

// ---------------------------------------------------------------------------
// Merged weight transpose+convert: all 8 jobs (4 weights x 2 layers) in one
// launch. Grid (768, 2): t<192 qkv | <256 proj | <512 fc1 | else fc2.
__global__ __launch_bounds__(256) void wconv_all(
    const float* __restrict__ qkv_w, const float* __restrict__ proj_w,
    const float* __restrict__ fc1_w, const float* __restrict__ fc2_w,
    ushort_t* __restrict__ wq_t, ushort_t* __restrict__ wp_t,
    ushort_t* __restrict__ w1_t, ushort_t* __restrict__ w2_t)
{
    __shared__ float t_[32][33];
    int l = blockIdx.y, t = blockIdx.x;
    const float* W; ushort_t* Wt; int K, N, n0, k0;
    if (t < 192)      { W = qkv_w  + (size_t)l*EE*3*EE; Wt = wq_t + (size_t)l*3*EE*EE;
                        K = EE; N = 3*EE; int u = t;       n0 = (u % 24) * 32; k0 = (u / 24) * 32; }
    else if (t < 256) { W = proj_w + (size_t)l*EE*EE;   Wt = wp_t + (size_t)l*EE*EE;
                        K = EE; N = EE;   int u = t - 192; n0 = (u % 8)  * 32; k0 = (u / 8)  * 32; }
    else if (t < 512) { W = fc1_w  + (size_t)l*EE*NI;   Wt = w1_t + (size_t)l*EE*NI;
                        K = EE; N = NI;   int u = t - 256; n0 = (u % 32) * 32; k0 = (u / 32) * 32; }
    else              { W = fc2_w  + (size_t)l*NI*EE;   Wt = w2_t + (size_t)l*NI*EE;
                        K = NI; N = EE;   int u = t - 512; n0 = (u % 8)  * 32; k0 = (u / 8)  * 32; }
    int tx = threadIdx.x & 31, ty = threadIdx.x >> 5;
    #pragma unroll
    for (int i = 0; i < 4; ++i) {
        int k = ty + i * 8;
        t_[k][tx] = W[(size_t)(k0 + k) * N + n0 + tx];
    }
    __syncthreads();
    #pragma unroll
    for (int i = 0; i < 4; ++i) {
        int n = ty + i * 8;
        Wt[(size_t)(n0 + n) * K + k0 + tx] = f2bf(t_[tx][n]);
    }
}

// ---------------------------------------------------------------------------
// bf16 MFMA GEMM: C[M,N] = act( A[M,K] @ Wt[N,K]^T + bias [+ res] )
// MI = M-frags per wave: MI=2 -> BM=128, MI=1 -> BM=64 (skinny-N GEMMs).
// QSC: pre-scale cols<EE by QSCALE (softmax scale + log2e fold).
template<int MI, bool OUT_BF, bool GELU_ACT, bool RES, bool QSC>
__global__ __launch_bounds__(256) void gemm_bf(
    const ushort_t* __restrict__ A, const ushort_t* __restrict__ Bt,
    const float* __restrict__ bias, const float* __restrict__ res,
    void* __restrict__ C, int M, int N, int K)
{
    __shared__ __align__(16) ushort_t As[MI*64][40];
    __shared__ __align__(16) ushort_t Bs[64][40];
    int tid = threadIdx.x;
    int wid = tid >> 6, lane = tid & 63;
    int h = lane >> 4, c = lane & 15;
    int bx = blockIdx.x, by = blockIdx.y;

    f32x4 acc[MI][4] = {};

    int arow = tid >> 2, ac = tid & 3;
    const ushort_t* Ap = A  + (size_t)(by * (MI*64) + arow) * K + ac * 8;
    const ushort_t* Bp = Bt + (size_t)(bx * 64     + arow) * K + ac * 8;

    for (int k0 = 0; k0 < K; k0 += 32) {
        s16x8 av[MI];
        #pragma unroll
        for (int i = 0; i < MI; ++i)
            av[i] = *(const s16x8*)(Ap + (size_t)i * 64 * K + k0);
        s16x8 b0 = *(const s16x8*)(Bp + k0);
        __syncthreads();
        #pragma unroll
        for (int i = 0; i < MI; ++i)
            *(s16x8*)&As[i * 64 + arow][ac * 8] = av[i];
        *(s16x8*)&Bs[arow][ac * 8] = b0;
        __syncthreads();

        s16x8 af[MI], bfr[4];
        #pragma unroll
        for (int i = 0; i < MI; ++i)
            af[i] = *(const s16x8*)&As[wid * (MI*16) + i * 16 + c][h * 8];
        #pragma unroll
        for (int j = 0; j < 4; ++j)
            bfr[j] = *(const s16x8*)&Bs[j * 16 + c][h * 8];
        #pragma unroll
        for (int i = 0; i < MI; ++i)
            #pragma unroll
            for (int j = 0; j < 4; ++j)
                acc[i][j] = mfma16x16x32(af[i], bfr[j], acc[i][j]);
    }

    float bj[4];
    #pragma unroll
    for (int j = 0; j < 4; ++j) bj[j] = bias[bx * 64 + j * 16 + c];
    #pragma unroll
    for (int i = 0; i < MI; ++i) {
        #pragma unroll
        for (int r = 0; r < 4; ++r) {
            int row = by * (MI*64) + wid * (MI*16) + i * 16 + h * 4 + r;
            #pragma unroll
            for (int j = 0; j < 4; ++j) {
                int col = bx * 64 + j * 16 + c;
                float v = acc[i][j][r] + bj[j];
                if (QSC && col < EE) v *= QSCALE;
                if (RES) v += res[(size_t)row * N + col];
                if (GELU_ACT) {
                    float t = v;
                    v = 0.5f * t * (1.f + tanhf(0.7978845608028654f *
                                                (t + 0.044715f * t * t * t)));
                }
                if (OUT_BF) ((ushort_t*)C)[(size_t)row * N + col] = f2bf(v);
                else        ((float*)C)[(size_t)row * N + col]    = v;
            }
        }
    }
}

// ---------------------------------------------------------------------------
// Split-K causal flash attention (partial pass). PTILES=8, 80 pieces/(b,h).
// ROUND-12: 128-key PASSES (two 64-key tiles per softmax pass) — softmax was
// the bottleneck (VALUBusy 48%, MfmaUtil 5%): the max/psum shfl reductions,
// corr exp + O-rescale, and barrier pair are paid once per 128 keys instead
// of per 64. All exps are exp2f (scores pre-scaled by log2e in the QKV GEMM).
// Odd-tile tail: B-half loads clamp to the last tile; causal mask (keys >=
// (qt+1)*64 > qrow) kills the duplicate. LDS 39.4KB -> 4 blocks/CU.
#define QB 64
#define KSTR 40
#define VSTR 184
#define PSTR 136
#define PTILES 8
__global__ __launch_bounds__(256) void attn_kernel(
    const ushort_t* __restrict__ qkv, ushort_t* __restrict__ o_part,
    float* __restrict__ ml_part)
{
    __shared__ __align__(16) ushort_t Ks[128][KSTR];
    __shared__ __align__(16) ushort_t Vt[DD][VSTR];
    __shared__ __align__(16) ushort_t Ps[4][16][PSTR];

    int tid  = threadIdx.x;
    int p    = 79 - blockIdx.x;              // heavy (high qt) first
    int qt, ks;
    if (p < 8)       { qt = p;                 ks = 0; }
    else if (p < 24) { qt = 8  + ((p-8)  >> 1); ks = (p-8)  & 1; }
    else if (p < 48) { qt = 16 + (p-24) / 3;    ks = (p-24) % 3; }
    else             { qt = 24 + ((p-48) >> 2); ks = (p-48) & 3; }
    int hh   = blockIdx.y, b = blockIdx.z;
    int wid  = tid >> 6, lane = tid & 63;
    int h    = lane >> 4, c = lane & 15;

    // Q A-frag: lane holds Q[row=c][h*8+j] (pre-scaled by QSCALE)
    int qfrow = qt * QB + wid * 16 + c;
    s16x8 qfrag = *(const s16x8*)(qkv + ((size_t)(b * SS + qfrow)) * (3*EE)
                                  + hh * DD + h * 8);

    f32x4 o0 = {0.f,0.f,0.f,0.f}, o1 = {0.f,0.f,0.f,0.f};
    float m[4] = { -INFINITY, -INFINITY, -INFINITY, -INFINITY };
    float l[4] = { 0.f, 0.f, 0.f, 0.f };

    int srow = tid >> 2, scq = tid & 3;
    int t0 = ks * PTILES;
    int t1 = min(t0 + PTILES, qt + 1);
    int npass = (t1 - t0 + 1) >> 1;

    // prologue: load pass 0's two tiles into regs (B clamped for odd tails)
    s16x8 kregA, vregA, kregB, vregB;
    {
        const ushort_t* ka = qkv + ((size_t)(b * SS + t0 * QB)) * (3*EE) + hh * DD + EE;
        int tb = min(t0 + 1, t1 - 1);
        const ushort_t* kb = qkv + ((size_t)(b * SS + tb * QB)) * (3*EE) + hh * DD + EE;
        kregA = *(const s16x8*)(ka + (size_t)srow * (3*EE) + scq * 8);
        vregA = *(const s16x8*)(ka + EE + (size_t)srow * (3*EE) + scq * 8);
        kregB = *(const s16x8*)(kb + (size_t)srow * (3*EE) + scq * 8);
        vregB = *(const s16x8*)(kb + EE + (size_t)srow * (3*EE) + scq * 8);
    }

    for (int ps = 0; ps < npass; ++ps) {
        int kA = t0 + 2 * ps;
        int k0 = kA * QB;

        __syncthreads();   // prev pass's LDS reads done

        // stage both tiles from regs
        *(s16x8*)&Ks[srow][scq * 8]      = kregA;
        *(s16x8*)&Ks[64 + srow][scq * 8] = kregB;
        {
            int d0 = scq * 8;
            int colw = srow ^ (scq << 4);
            #pragma unroll
            for (int j = 0; j < 8; ++j) {
                Vt[d0 + j][colw]      = (ushort_t)vregA[j];
                Vt[d0 + j][64 + colw] = (ushort_t)vregB[j];
            }
        }
        // prefetch next pass (stays in flight across the barrier)
        if (ps + 1 < npass) {
            int a2 = kA + 2, b2 = min(a2 + 1, t1 - 1);
            const ushort_t* ka2 = qkv + ((size_t)(b * SS + a2 * QB)) * (3*EE) + hh * DD + EE;
            const ushort_t* kb2 = qkv + ((size_t)(b * SS + b2 * QB)) * (3*EE) + hh * DD + EE;
            kregA = *(const s16x8*)(ka2 + (size_t)srow * (3*EE) + scq * 8);
            vregA = *(const s16x8*)(ka2 + EE + (size_t)srow * (3*EE) + scq * 8);
            kregB = *(const s16x8*)(kb2 + (size_t)srow * (3*EE) + scq * 8);
            vregB = *(const s16x8*)(kb2 + EE + (size_t)srow * (3*EE) + scq * 8);
        }

        // barrier that waits DS only (NOT vmcnt): prefetch overlaps compute
        asm volatile("s_waitcnt lgkmcnt(0)" ::: "memory");
        __builtin_amdgcn_s_barrier();
        asm volatile("" ::: "memory");

        __builtin_amdgcn_s_setprio(1);

        // QK: 8 mfmas over 128 keys
        f32x4 sg[8];
        #pragma unroll
        for (int g = 0; g < 8; ++g) {
            s16x8 kf = *(const s16x8*)&Ks[g * 16 + c][h * 8];
            f32x4 z = {0.f,0.f,0.f,0.f};
            sg[g] = mfma16x16x32(qfrag, kf, z);
        }

        bool needMask = (kA + 1 >= qt);   // wave-uniform

        // softmax rows R = h*4+r over 128 keys
        #pragma unroll
        for (int r = 0; r < 4; ++r) {
            float sv[8];
            #pragma unroll
            for (int g = 0; g < 8; ++g) sv[g] = sg[g][r];
            if (needMask) {
                int qrow = qt * QB + wid * 16 + h * 4 + r;
                #pragma unroll
                for (int g = 0; g < 8; ++g)
                    if (k0 + g * 16 + c > qrow) sv[g] = -INFINITY;
            }
            float bm = fmaxf(fmaxf(fmaxf(sv[0], sv[1]), fmaxf(sv[2], sv[3])),
                             fmaxf(fmaxf(sv[4], sv[5]), fmaxf(sv[6], sv[7])));
            #pragma unroll
            for (int off = 1; off <= 8; off <<= 1) bm = fmaxf(bm, __shfl_xor(bm, off));
            float nm   = fmaxf(m[r], bm);
            float corr = exp2f(m[r] - nm);   // exp2(-inf)=0 on first pass
            m[r] = nm;
            float psum = 0.f;
            #pragma unroll
            for (int g = 0; g < 8; ++g) {
                float pf = exp2f(sv[g] - nm);   // masked: exp2(-inf)=0
                Ps[wid][h * 4 + r][g * 16 + c] = f2bf(pf);
                psum += pf;
            }
            #pragma unroll
            for (int off = 1; off <= 8; off <<= 1) psum += __shfl_xor(psum, off);
            l[r] = l[r] * corr + psum;
            o0[r] *= corr;
            o1[r] *= corr;
        }

        // PV: 4 kc x 2 dc mfmas (Vt reads follow the XOR swizzle; the XOR
        // touches only bit 4, so the tile-B bit (64) passes through)
        #pragma unroll
        for (int kc = 0; kc < 4; ++kc) {
            int kbase = kc * 32 + h * 8;
            s16x8 pf = *(const s16x8*)&Ps[wid][c][kbase];
            s16x8 v0 = *(const s16x8*)&Vt[c]     [kbase ^ ((c >> 3) << 4)];
            s16x8 v1 = *(const s16x8*)&Vt[16 + c][kbase ^ (((16 + c) >> 3) << 4)];
            o0 = mfma16x16x32(pf, v0, o0);
            o1 = mfma16x16x32(pf, v1, o1);
        }

        __builtin_amdgcn_s_setprio(0);
    }

    // write partials (unnormalized O in bf16; m,l in f32; m in log2 domain)
    size_t rbase = (size_t)(b * HH + hh) * SS;
    #pragma unroll
    for (int r = 0; r < 4; ++r) {
        int qrow = qt * QB + wid * 16 + h * 4 + r;
        size_t rl = rbase + qrow;
        ushort_t* op = o_part + ((size_t)ks * NRL + rl) * DD;
        op[c]      = f2bf(o0[r]);
        op[16 + c] = f2bf(o1[r]);
        if (c == 0) {
            float* mp = ml_part + ((size_t)ks * NRL + rl) * 2;
            mp[0] = m[r];
            mp[1] = l[r];
        }
    }
}

// ---------------------------------------------------------------------------
// Merge <=4 split-K partials per (b,h,s) row -> attno bf16 (log2-domain m).
__global__ __launch_bounds__(256) void attn_merge(
    const ushort_t* __restrict__ o_part, const float* __restrict__ ml_part,
    ushort_t* __restrict__ attno)
{
    int g = blockIdx.x * 256 + threadIdx.x;   // 0 .. NRL*8-1
    int rl = g >> 3;
    int d0 = (g & 7) * 4;
    int srow = rl & (SS - 1);
    int qt = srow >> 6;
    int np = (qt >> 3) + 1;                   // ceil((qt+1)/PTILES)

    float mv[4], lv[4];
    float M = -INFINITY;
    #pragma unroll
    for (int i = 0; i < 4; ++i) {
        if (i < np) {
            const float* mp = ml_part + ((size_t)i * NRL + rl) * 2;
            mv[i] = mp[0]; lv[i] = mp[1];
            M = fmaxf(M, mv[i]);
        }
    }
    float acc0 = 0.f, acc1 = 0.f, acc2 = 0.f, acc3 = 0.f, L = 0.f;
    #pragma unroll
    for (int i = 0; i < 4; ++i) {
        if (i < np) {
            float w = exp2f(mv[i] - M);
            L += w * lv[i];
            ushort4 ov = *(const ushort4*)(o_part + ((size_t)i * NRL + rl) * DD + d0);
            acc0 += w * bf2f(ov.x); acc1 += w * bf2f(ov.y);
            acc2 += w * bf2f(ov.z); acc3 += w * bf2f(ov.w);
        }
    }
    float inv = 1.f / L;
    int b  = rl >> 14;           // /(HH*SS)
    int hh = (rl >> 11) & 7;     // /SS % HH
    ushort4 w4 = { f2bf(acc0*inv), f2bf(acc1*inv), f2bf(acc2*inv), f2bf(acc3*inv) };
    *(ushort4*)(attno + ((size_t)(b * SS + srow)) * EE + hh * DD + d0) = w4;
}

// ---------------------------------------------------------------------------
extern "C" void kernel_launch(void* const* d_in, const int* in_sizes, int n_in,
                              void* d_out, int out_size, void* d_ws, size_t ws_size,
                              hipStream_t stream)
{
    const int*   ids    = (const int*)  d_in[0];
    const float* wte    = (const float*)d_in[1];
    const float* wpe    = (const float*)d_in[2];
    const float* ln1_g  = (const float*)d_in[3];
    const float* ln1_b  = (const float*)d_in[4];
    const float* qkv_w  = (const float*)d_in[5];
    const float* qkv_b  = (const float*)d_in[6];
    const float* proj_w = (const float*)d_in[7];
    const float* proj_b = (const float*)d_in[8];
    const float* ln2_g  = (const float*)d_in[9];
    const float* ln2_b  = (const float*)d_in[10];
    const float* fc1_w  = (const float*)d_in[11];
    const float* fc1_b  = (const float*)d_in[12];
    const float* fc2_w  = (const float*)d_in[13];
    const float* fc2_b  = (const float*)d_in[14];
    const float* lnf_g  = (const float*)d_in[15];
    const float* lnf_b  = (const float*)d_in[16];

    float*    h        = (float*)d_ws;                         // 8192*256 f32
    ushort_t* x_bf     = (ushort_t*)(h + (size_t)NROWS*EE);    // 8192*256
    ushort_t* qkv_bf   = x_bf   + (size_t)NROWS*EE;            // 8192*768
    ushort_t* attno_bf = qkv_bf + (size_t)NROWS*3*EE;          // 8192*256
    ushort_t* m1_bf    = attno_bf + (size_t)NROWS*EE;          // 8192*1024
    ushort_t* wq_t     = m1_bf  + (size_t)NROWS*NI;            // [2][768][256]
    ushort_t* wp_t     = wq_t   + (size_t)2*3*EE*EE;           // [2][256][256]
    ushort_t* w1_t     = wp_t   + (size_t)2*EE*EE;             // [2][1024][256]
    ushort_t* w2_t     = w1_t   + (size_t)2*EE*NI;             // [2][256][1024]

    // split-K scratch overlays (regions dead during attention):
    ushort_t* o_part   = m1_bf;              // 4*65536*32*2B = 16.78MB == m1 region
    float*    ml_part  = (float*)x_bf;       // 4*65536*2*4B  = 2.1MB   <  x region

    // one-time (per call) weight transpose+convert — single launch
    wconv_all<<<dim3(768, LL), 256, 0, stream>>>(
        qkv_w, proj_w, fc1_w, fc2_w, wq_t, wp_t, w1_t, w2_t);

    // fused embedding + LN1(layer 0)
    embed_ln_kernel<<<NROWS/4, 256, 0, stream>>>(ids, wte, wpe, ln1_g, ln1_b, h, x_bf);

    for (int l = 0; l < LL; ++l) {
        if (l > 0)
            ln_kernel<true><<<NROWS/4, 256, 0, stream>>>(h, ln1_g + l*EE, ln1_b + l*EE, x_bf);
        gemm_bf<2,true,false,false,true><<<dim3(3*EE/64, NROWS/128), 256, 0, stream>>>(
            x_bf, wq_t + (size_t)l*3*EE*EE, qkv_b + (size_t)l*3*EE, nullptr,
            qkv_bf, NROWS, 3*EE, EE);
        attn_kernel<<<dim3(80, HH, BB), 256, 0, stream>>>(qkv_bf, o_part, ml_part);
        attn_merge<<<NRL*8/256, 256, 0, stream>>>(o_part, ml_part, attno_bf);
        gemm_bf<1,false,false,true,false><<<dim3(EE/64, NROWS/64), 256, 0, stream>>>(
            attno_bf, wp_t + (size_t)l*EE*EE, proj_b + (size_t)l*EE, h,
            h, NROWS, EE, EE);
        ln_kernel<true><<<NROWS/4, 256, 0, stream>>>(h, ln2_g + l*EE, ln2_b + l*EE, x_bf);
        gemm_bf<2,true,true,false,false><<<dim3(NI/64, NROWS/128), 256, 0, stream>>>(
            x_bf, w1_t + (size_t)l*EE*NI, fc1_b + (size_t)l*NI, nullptr,
            m1_bf, NROWS, NI, EE);
        gemm_bf<1,false,false,true,false><<<dim3(EE/64, NROWS/64), 256, 0, stream>>>(
            m1_bf, w2_t + (size_t)l*NI*EE, fc2_b + (size_t)l*EE, h,
            h, NROWS, EE, NI);
    }

    ln_kernel<false><<<NROWS/4, 256, 0, stream>>>(h, lnf_g, lnf_b, (float*)d_out);
}